// Round 1
// baseline (491.736 us; speedup 1.0000x reference)
//
#include <hip/hip_runtime.h>
#include <cstddef>

#define BATCH  8192
#define NFEAT  4096
#define NGRP   256
#define NSPLIT 253
#define NH1    512
#define NH2    256
#define EPSV   1e-5f

__constant__ int c_prefix[8] = {0,3,8,16,28,44,65,92};
__constant__ int c_gsize[8]  = {3,5,8,12,16,21,27,36};

// ---------------------------------------------------------------------------
// Kernel 1: gene[b,g] = relu(sum_{f in group g} x[b,f]*w[f] + bg[g])
// One block per row; stage x[row]*w into LDS (16 KB), then one thread per group.
// ---------------------------------------------------------------------------
__global__ __launch_bounds__(256) void gene_kernel(const float* __restrict__ x,
        const float* __restrict__ wg, const float* __restrict__ bg,
        float* __restrict__ gene)
{
    __shared__ float prod[NFEAT];
    int t = threadIdx.x;
    size_t row = blockIdx.x;
    const float4* xv = (const float4*)(x + row * NFEAT);
    const float4* wv = (const float4*)wg;
    float4* pv = (float4*)prod;
#pragma unroll
    for (int i = 0; i < 4; i++) {
        int idx = t + 256 * i;
        float4 a = xv[idx], w = wv[idx];
        float4 p; p.x = a.x*w.x; p.y = a.y*w.y; p.z = a.z*w.z; p.w = a.w*w.w;
        pv[idx] = p;
    }
    __syncthreads();
    int g = t;
    int start = (g >> 3) * 128 + c_prefix[g & 7];
    int len = c_gsize[g & 7];
    float s = 0.f;
    for (int i = 0; i < len; i++) s += prod[start + i];
    s += bg[g];
    gene[row * NGRP + g] = fmaxf(s, 0.f);
}

// ---------------------------------------------------------------------------
// Generic fp32 GEMM: C = op(A)[M x K] @ W[K x N] + bias, with fused per-column
// sum / sumsq accumulation (for downstream BatchNorm) and optional fused
// BN+ReLU applied to A on load (op). 64x64 tile, 256 threads, 4x4 microtile.
// lda may exceed K (gene buffer): reads beyond K are in-bounds and zeroed.
// ---------------------------------------------------------------------------
__global__ __launch_bounds__(256) void gemm_kernel(
    const float* __restrict__ A, int lda, int K,
    const float* __restrict__ W, int n_total,   // ldw == ldc == n_total
    const float* __restrict__ bias,
    float* __restrict__ C,
    float* __restrict__ csum, float* __restrict__ csq,
    const float* __restrict__ a_sum, const float* __restrict__ a_sq,
    const float* __restrict__ a_gamma, const float* __restrict__ a_beta)
{
    __shared__ float As[16][68];   // [k][m], padded
    __shared__ float Bs[16][68];   // [k][n], padded
    __shared__ float bnsc[512];
    __shared__ float bnsh[512];

    int t  = threadIdx.x;
    int tx = t & 15, ty = t >> 4;
    int n0 = blockIdx.x * 64;
    int m0 = blockIdx.y * 64;
    bool bn = (a_sum != nullptr);
    if (bn) {
        const float invB = 1.f / (float)BATCH;
        for (int k = t; k < K; k += 256) {
            float mu  = a_sum[k] * invB;
            float var = a_sq[k] * invB - mu * mu;
            float sc  = a_gamma[k] * rsqrtf(var + EPSV);
            bnsc[k] = sc;
            bnsh[k] = a_beta[k] - mu * sc;
        }
    }

    float acc[4][4];
#pragma unroll
    for (int i = 0; i < 4; i++)
#pragma unroll
        for (int j = 0; j < 4; j++) acc[i][j] = 0.f;

    int nk   = (K + 15) >> 4;
    int arow = t >> 2;          // 0..63
    int k4   = (t & 3) * 4;     // 0,4,8,12
    int wn   = t & 63;
    int wkr  = t >> 6;          // 0..3

    for (int kt = 0; kt < nk; kt++) {
        int kk = kt << 4;
        __syncthreads();        // also covers bn-table init on first iter
        // Stage A: float4 load + transpose scatter (2-way bank alias only)
        {
            const float4 va = *(const float4*)(A + (size_t)(m0 + arow) * lda + kk + k4);
            float v[4] = {va.x, va.y, va.z, va.w};
#pragma unroll
            for (int c = 0; c < 4; c++) {
                int kg = kk + k4 + c;
                float val = (kg < K) ? v[c] : 0.f;
                if (bn && kg < K) val = fmaxf(fmaf(val, bnsc[kg], bnsh[kg]), 0.f);
                As[k4 + c][arow] = val;
            }
        }
        // Stage W: coalesced rows
        {
#pragma unroll
            for (int i = 0; i < 4; i++) {
                int k  = wkr + i * 4;
                int kg = kk + k;
                Bs[k][wn] = (kg < K) ? W[(size_t)kg * n_total + n0 + wn] : 0.f;
            }
        }
        __syncthreads();
#pragma unroll
        for (int k = 0; k < 16; k++) {
            float4 a = *(const float4*)&As[k][ty * 4];
            float4 b = *(const float4*)&Bs[k][tx * 4];
            float av[4] = {a.x, a.y, a.z, a.w};
            float bv[4] = {b.x, b.y, b.z, b.w};
#pragma unroll
            for (int i = 0; i < 4; i++)
#pragma unroll
                for (int j = 0; j < 4; j++)
                    acc[i][j] = fmaf(av[i], bv[j], acc[i][j]);
        }
    }

    // Epilogue: bias add, store C, per-column sum/sumsq via LDS + atomics
    int row0 = m0 + ty * 4, col0 = n0 + tx * 4;
    float cs[4] = {0, 0, 0, 0}, cq[4] = {0, 0, 0, 0};
#pragma unroll
    for (int i = 0; i < 4; i++) {
        float4 o;
        float* op = &o.x;
#pragma unroll
        for (int j = 0; j < 4; j++) {
            float cval = acc[i][j] + bias[col0 + j];
            op[j] = cval;
            cs[j] += cval;
            cq[j] += cval * cval;
        }
        *(float4*)(C + (size_t)(row0 + i) * n_total + col0) = o;
    }
    __syncthreads();   // done with As/Bs as tiles
#pragma unroll
    for (int j = 0; j < 4; j++) { As[ty][tx * 4 + j] = cs[j]; Bs[ty][tx * 4 + j] = cq[j]; }
    __syncthreads();
    if (t < 64) {
        float s = 0.f, q = 0.f;
#pragma unroll
        for (int r = 0; r < 16; r++) { s += As[r][t]; q += Bs[r][t]; }
        atomicAdd(&csum[n0 + t], s);
        atomicAdd(&csq[n0 + t], q);
    }
}

// ---------------------------------------------------------------------------
// Branch 2 layer 1: out[b,:] = g2[b,0:3] @ W1g2[3,512] + b1g2, K=3.
// 16 rows per block, stats fused.
// ---------------------------------------------------------------------------
__global__ __launch_bounds__(256) void b2l1_kernel(const float* __restrict__ gene,
    const float* __restrict__ W, const float* __restrict__ bias,
    float* __restrict__ out, float* __restrict__ csum, float* __restrict__ csq)
{
    __shared__ float Ws[3 * 512];
    __shared__ float bsh[512];
    __shared__ float gv[16][3];
    int t = threadIdx.x;
    for (int i = t; i < 1536; i += 256) Ws[i] = W[i];
    for (int i = t; i < 512; i += 256) bsh[i] = bias[i];
    int row0 = blockIdx.x * 16;
    if (t < 48) gv[t / 3][t % 3] = gene[(size_t)(row0 + t / 3) * NGRP + NSPLIT + (t % 3)];
    __syncthreads();
    int c0 = t, c1 = t + 256;
    float s0 = 0, q0 = 0, s1 = 0, q1 = 0;
    for (int r = 0; r < 16; r++) {
        float a = gv[r][0], b = gv[r][1], c = gv[r][2];
        float v0 = bsh[c0] + a * Ws[c0] + b * Ws[512 + c0] + c * Ws[1024 + c0];
        float v1 = bsh[c1] + a * Ws[c1] + b * Ws[512 + c1] + c * Ws[1024 + c1];
        size_t base = (size_t)(row0 + r) * NH1;
        out[base + c0] = v0; out[base + c1] = v1;
        s0 += v0; q0 += v0 * v0; s1 += v1; q1 += v1 * v1;
    }
    atomicAdd(&csum[c0], s0); atomicAdd(&csq[c0], q0);
    atomicAdd(&csum[c1], s1); atomicAdd(&csq[c1], q1);
}

// ---------------------------------------------------------------------------
// Final: out[b] = bnrelu(h1b)@Wout[0:256] + bnrelu(h2b)@Wout[256:512]
//               + gene[b,:]@Wres + b_out + b_res.   One wave per row.
// ---------------------------------------------------------------------------
__global__ __launch_bounds__(256) void final_kernel(
    const float* __restrict__ h1, const float* __restrict__ h2, const float* __restrict__ gene,
    const float* __restrict__ s1, const float* __restrict__ q1,
    const float* __restrict__ gm1, const float* __restrict__ bt1,
    const float* __restrict__ s2, const float* __restrict__ q2,
    const float* __restrict__ gm2, const float* __restrict__ bt2,
    const float* __restrict__ Wout, const float* __restrict__ bo,
    const float* __restrict__ Wres, const float* __restrict__ br,
    float* __restrict__ outp)
{
    int t = threadIdx.x, lane = t & 63, wv = t >> 6;
    int row = blockIdx.x * 4 + wv;
    const float invB = 1.f / (float)BATCH;
    float acc = 0.f;
#pragma unroll
    for (int ii = 0; ii < 4; ii++) {
        int c = lane + ii * 64;
        float mu  = s1[c] * invB;
        float var = q1[c] * invB - mu * mu;
        float sc  = gm1[c] * rsqrtf(var + EPSV);
        float v   = (h1[(size_t)row * NH2 + c] - mu) * sc + bt1[c];
        acc += fmaxf(v, 0.f) * Wout[c];
        mu  = s2[c] * invB;
        var = q2[c] * invB - mu * mu;
        sc  = gm2[c] * rsqrtf(var + EPSV);
        v   = (h2[(size_t)row * NH2 + c] - mu) * sc + bt2[c];
        acc += fmaxf(v, 0.f) * Wout[NH2 + c];
        acc += gene[(size_t)row * NGRP + c] * Wres[c];
    }
#pragma unroll
    for (int off = 32; off > 0; off >>= 1) acc += __shfl_down(acc, off, 64);
    if (lane == 0) outp[row] = acc + bo[0] + br[0];
}

extern "C" void kernel_launch(void* const* d_in, const int* in_sizes, int n_in,
                              void* d_out, int out_size, void* d_ws, size_t ws_size,
                              hipStream_t stream)
{
    (void)in_sizes; (void)n_in; (void)out_size; (void)ws_size;
    const float* x        = (const float*)d_in[0];
    // d_in[1] = seg: pattern is compile-time known, unused
    const float* wgene    = (const float*)d_in[2];
    const float* bgene    = (const float*)d_in[3];
    const float* W1g1     = (const float*)d_in[4];
    const float* b1g1     = (const float*)d_in[5];
    const float* W2g1     = (const float*)d_in[6];
    const float* b2g1     = (const float*)d_in[7];
    const float* W1g2     = (const float*)d_in[8];
    const float* b1g2     = (const float*)d_in[9];
    const float* W2g2     = (const float*)d_in[10];
    const float* b2g2     = (const float*)d_in[11];
    const float* gamma1g1 = (const float*)d_in[12];
    const float* beta1g1  = (const float*)d_in[13];
    const float* gamma2g1 = (const float*)d_in[14];
    const float* beta2g1  = (const float*)d_in[15];
    const float* gamma1g2 = (const float*)d_in[16];
    const float* beta1g2  = (const float*)d_in[17];
    const float* gamma2g2 = (const float*)d_in[18];
    const float* beta2g2  = (const float*)d_in[19];
    const float* Wout     = (const float*)d_in[20];
    const float* bout     = (const float*)d_in[21];
    const float* Wres     = (const float*)d_in[22];
    const float* bres     = (const float*)d_in[23];
    float* outp = (float*)d_out;

    // Workspace layout (fp32): gene | bufA (h1-l1pre, reused for h2-l1pre) | h1b | h2b | stats
    float* gene = (float*)d_ws;
    float* bufA = gene + (size_t)BATCH * NGRP;
    float* h1b  = bufA + (size_t)BATCH * NH1;
    float* h2b  = h1b  + (size_t)BATCH * NH2;
    float* st   = h2b  + (size_t)BATCH * NH2;
    float* s1a = st;          float* q1a = st + 512;
    float* s1b = st + 1024;   float* q1b = st + 1536;
    float* s2a = st + 2048;   float* q2a = st + 2560;
    float* s2b = st + 3072;   float* q2b = st + 3584;

    hipMemsetAsync(st, 0, 4096 * sizeof(float), stream);

    gene_kernel<<<BATCH, 256, 0, stream>>>(x, wgene, bgene, gene);

    // layer1 branch1: gene[:, :253] @ W1g1 + b1g1  -> bufA, stats s1a/q1a
    gemm_kernel<<<dim3(NH1 / 64, BATCH / 64), 256, 0, stream>>>(
        gene, NGRP, NSPLIT, W1g1, NH1, b1g1, bufA, s1a, q1a,
        nullptr, nullptr, nullptr, nullptr);

    // layer2 branch1: bnrelu(bufA) @ W2g1 + b2g1 -> h1b, stats s1b/q1b
    gemm_kernel<<<dim3(NH2 / 64, BATCH / 64), 256, 0, stream>>>(
        bufA, NH1, NH1, W2g1, NH2, b2g1, h1b, s1b, q1b,
        s1a, q1a, gamma1g1, beta1g1);

    // layer1 branch2: gene[:, 253:256] @ W1g2 + b1g2 -> bufA (reuse), stats s2a/q2a
    b2l1_kernel<<<BATCH / 16, 256, 0, stream>>>(gene, W1g2, b1g2, bufA, s2a, q2a);

    // layer2 branch2: bnrelu(bufA) @ W2g2 + b2g2 -> h2b, stats s2b/q2b
    gemm_kernel<<<dim3(NH2 / 64, BATCH / 64), 256, 0, stream>>>(
        bufA, NH1, NH1, W2g2, NH2, b2g2, h2b, s2b, q2b,
        s2a, q2a, gamma1g2, beta1g2);

    final_kernel<<<BATCH / 4, 256, 0, stream>>>(
        h1b, h2b, gene,
        s1b, q1b, gamma2g1, beta2g1,
        s2b, q2b, gamma2g2, beta2g2,
        Wout, bout, Wres, bres, outp);
}

// Round 2
// 322.374 us; speedup vs baseline: 1.5254x; 1.5254x over previous
//
#include <hip/hip_runtime.h>
#include <cstddef>

#define BATCH  8192
#define NFEAT  4096
#define NGRP   256
#define NSPLIT 253
#define NH1    512
#define NH2    256
#define EPSV   1e-5f

typedef __bf16 bf16_8 __attribute__((ext_vector_type(8)));
typedef float  f32x4  __attribute__((ext_vector_type(4)));

__constant__ int c_prefix[8] = {0,3,8,16,28,44,65,92};
__constant__ int c_gsize[8]  = {3,5,8,12,16,21,27,36};

// ---------------------------------------------------------------------------
// Kernel 1: gene[b,g] = relu(sum_{f in group g} x[b,f]*w[f] + bg[g])
// Writes fp32 gene (residual / b2l1 / final) and bf16 copy (GEMM1 A).
// ---------------------------------------------------------------------------
__global__ __launch_bounds__(256) void gene_kernel(const float* __restrict__ x,
        const float* __restrict__ wg, const float* __restrict__ bg,
        float* __restrict__ gene, __bf16* __restrict__ geneb)
{
    __shared__ float prod[NFEAT];
    int t = threadIdx.x;
    size_t row = blockIdx.x;
    const float4* xv = (const float4*)(x + row * NFEAT);
    const float4* wv = (const float4*)wg;
    float4* pv = (float4*)prod;
#pragma unroll
    for (int i = 0; i < 4; i++) {
        int idx = t + 256 * i;
        float4 a = xv[idx], w = wv[idx];
        float4 p; p.x = a.x*w.x; p.y = a.y*w.y; p.z = a.z*w.z; p.w = a.w*w.w;
        pv[idx] = p;
    }
    __syncthreads();
    int g = t;
    int start = (g >> 3) * 128 + c_prefix[g & 7];
    int len = c_gsize[g & 7];
    float s = 0.f;
    for (int i = 0; i < len; i++) s += prod[start + i];
    s += bg[g];
    s = fmaxf(s, 0.f);
    gene[row * NGRP + g] = s;
    geneb[row * NGRP + g] = (__bf16)s;
}

// ---------------------------------------------------------------------------
// Transpose + convert weights: dst[n][k] = (bf16)src[k][n], zero-pad k in [K,Kp)
// ---------------------------------------------------------------------------
__global__ __launch_bounds__(256) void transposeW(const float* __restrict__ src,
        __bf16* __restrict__ dst, int K, int N, int Kp)
{
    __shared__ float tile[32][33];
    int kt = blockIdx.x * 32, nt = blockIdx.y * 32;
    int tx = threadIdx.x & 31, ty = threadIdx.x >> 5;   // 32 x 8
    for (int r = ty; r < 32; r += 8) {
        int k = kt + r, n = nt + tx;
        tile[r][tx] = (k < K && n < N) ? src[(size_t)k * N + n] : 0.f;
    }
    __syncthreads();
    for (int r = ty; r < 32; r += 8) {
        int n = nt + r, k = kt + tx;
        if (n < N && k < Kp) dst[(size_t)n * Kp + k] = (__bf16)tile[tx][r];
    }
}

// ---------------------------------------------------------------------------
// bf16 MFMA GEMM: C[M x N] = op(A)[M x K] @ WT^T + bias
//   A:  bf16 row-major, leading dim lda (K multiple of 64)
//   WT: bf16 N x K row-major (pre-transposed weights)
//   op: optional BN+ReLU on A using batch stats (a_sum/a_sq) + gamma/beta
//   C:  bf16; fused per-column sum/sumsq accumulation into csum/csq (fp32)
// 64x64 tile, BK=64, 256 threads = 4 waves (2x2), wave = 32x32 via
// mfma_f32_16x16x32_bf16. Fragment layouts per measured gfx950 mapping:
//   A/B operand: [m|n = lane&15][k = (lane>>4)*8 + j]
//   C/D:         col = lane&15, row = (lane>>4)*4 + reg
// ---------------------------------------------------------------------------
__global__ __launch_bounds__(256) void gemm_bf16(
    const __bf16* __restrict__ A, int lda, int K,
    const __bf16* __restrict__ WT, int n_total,
    const float* __restrict__ bias,
    __bf16* __restrict__ C,
    float* __restrict__ csum, float* __restrict__ csq,
    const float* __restrict__ a_sum, const float* __restrict__ a_sq,
    const float* __restrict__ a_gamma, const float* __restrict__ a_beta)
{
    __shared__ __align__(16) __bf16 As[64][72];   // stride 144 B (16B aligned)
    __shared__ __align__(16) __bf16 Bs[64][72];
    __shared__ float bnsc[512];
    __shared__ float bnsh[512];
    __shared__ float sred[64];
    __shared__ float qred[64];

    int t = threadIdx.x;
    int n0 = blockIdx.x * 64;
    int m0 = blockIdx.y * 64;
    bool bn = (a_sum != nullptr);
    if (bn) {
        const float invB = 1.f / (float)BATCH;
        for (int k = t; k < K; k += 256) {
            float mu  = a_sum[k] * invB;
            float var = a_sq[k] * invB - mu * mu;
            float sc  = a_gamma[k] * rsqrtf(var + EPSV);
            bnsc[k] = sc;
            bnsh[k] = a_beta[k] - mu * sc;
        }
    }
    if (t < 64) { sred[t] = 0.f; qred[t] = 0.f; }

    int lane = t & 63, w = t >> 6;
    int wm = (w & 1) * 32, wn = (w >> 1) * 32;
    int fm = lane & 15, quad = lane >> 4;

    f32x4 acc[2][2];
#pragma unroll
    for (int i = 0; i < 2; i++)
#pragma unroll
        for (int j = 0; j < 2; j++) acc[i][j] = (f32x4){0.f, 0.f, 0.f, 0.f};

    int r0 = t >> 3;          // 0..31
    int kc = (t & 7) * 8;     // 0..56

    int nk = K >> 6;
    for (int kt = 0; kt < nk; kt++) {
        int kk = kt << 6;
        __syncthreads();   // covers bn-table/sred init on iter 0, frag reads after
        // ---- stage A (optionally BN+ReLU) ----
#pragma unroll
        for (int h = 0; h < 2; h++) {
            int row = r0 + h * 32;
            uint4 raw = *(const uint4*)(A + (size_t)(m0 + row) * lda + kk + kc);
            if (bn) {
                __bf16 vals[8];
#pragma unroll
                for (int c = 0; c < 4; c++) {
                    unsigned uu = (&raw.x)[c];
                    int kg = kk + kc + 2 * c;
                    float flo = __uint_as_float(uu << 16);
                    float fhi = __uint_as_float(uu & 0xffff0000u);
                    flo = fmaxf(fmaf(flo, bnsc[kg],     bnsh[kg]),     0.f);
                    fhi = fmaxf(fmaf(fhi, bnsc[kg + 1], bnsh[kg + 1]), 0.f);
                    vals[2 * c]     = (__bf16)flo;
                    vals[2 * c + 1] = (__bf16)fhi;
                }
                *(bf16_8*)&As[row][kc] = *(bf16_8*)vals;
            } else {
                *(uint4*)&As[row][kc] = raw;
            }
        }
        // ---- stage B ----
#pragma unroll
        for (int h = 0; h < 2; h++) {
            int row = r0 + h * 32;
            *(uint4*)&Bs[row][kc] = *(const uint4*)(WT + (size_t)(n0 + row) * K + kk + kc);
        }
        __syncthreads();
        // ---- MFMA ----
#pragma unroll
        for (int kc2 = 0; kc2 < 64; kc2 += 32) {
            bf16_8 a0 = *(const bf16_8*)&As[wm + fm][kc2 + quad * 8];
            bf16_8 a1 = *(const bf16_8*)&As[wm + 16 + fm][kc2 + quad * 8];
            bf16_8 b0 = *(const bf16_8*)&Bs[wn + fm][kc2 + quad * 8];
            bf16_8 b1 = *(const bf16_8*)&Bs[wn + 16 + fm][kc2 + quad * 8];
            acc[0][0] = __builtin_amdgcn_mfma_f32_16x16x32_bf16(a0, b0, acc[0][0], 0, 0, 0);
            acc[0][1] = __builtin_amdgcn_mfma_f32_16x16x32_bf16(a0, b1, acc[0][1], 0, 0, 0);
            acc[1][0] = __builtin_amdgcn_mfma_f32_16x16x32_bf16(a1, b0, acc[1][0], 0, 0, 0);
            acc[1][1] = __builtin_amdgcn_mfma_f32_16x16x32_bf16(a1, b1, acc[1][1], 0, 0, 0);
        }
    }

    // ---- epilogue: bias, bf16 store, fused column stats ----
    float myS[2] = {0.f, 0.f}, myQ[2] = {0.f, 0.f};
#pragma unroll
    for (int j = 0; j < 2; j++) {
        int col = n0 + wn + j * 16 + fm;
        float bv = bias[col];
#pragma unroll
        for (int i = 0; i < 2; i++) {
#pragma unroll
            for (int r = 0; r < 4; r++) {
                float v = acc[i][j][r] + bv;
                int row = m0 + wm + i * 16 + quad * 4 + r;
                C[(size_t)row * n_total + col] = (__bf16)v;
                myS[j] += v;
                myQ[j] += v * v;
            }
        }
    }
#pragma unroll
    for (int j = 0; j < 2; j++) {
        atomicAdd(&sred[wn + j * 16 + fm], myS[j]);
        atomicAdd(&qred[wn + j * 16 + fm], myQ[j]);
    }
    __syncthreads();
    if (t < 64) {
        atomicAdd(&csum[n0 + t], sred[t]);
        atomicAdd(&csq[n0 + t], qred[t]);
    }
}

// ---------------------------------------------------------------------------
// Branch 2 layer 1: out[b,:] = g2[b,0:3] @ W1g2[3,512] + b1g2, K=3. bf16 out.
// ---------------------------------------------------------------------------
__global__ __launch_bounds__(256) void b2l1_kernel(const float* __restrict__ gene,
    const float* __restrict__ W, const float* __restrict__ bias,
    __bf16* __restrict__ out, float* __restrict__ csum, float* __restrict__ csq)
{
    __shared__ float Ws[3 * 512];
    __shared__ float bsh[512];
    __shared__ float gv[16][3];
    int t = threadIdx.x;
    for (int i = t; i < 1536; i += 256) Ws[i] = W[i];
    for (int i = t; i < 512; i += 256) bsh[i] = bias[i];
    int row0 = blockIdx.x * 16;
    if (t < 48) gv[t / 3][t % 3] = gene[(size_t)(row0 + t / 3) * NGRP + NSPLIT + (t % 3)];
    __syncthreads();
    int c0 = t, c1 = t + 256;
    float s0 = 0, q0 = 0, s1 = 0, q1 = 0;
    for (int r = 0; r < 16; r++) {
        float a = gv[r][0], b = gv[r][1], c = gv[r][2];
        float v0 = bsh[c0] + a * Ws[c0] + b * Ws[512 + c0] + c * Ws[1024 + c0];
        float v1 = bsh[c1] + a * Ws[c1] + b * Ws[512 + c1] + c * Ws[1024 + c1];
        size_t base = (size_t)(row0 + r) * NH1;
        out[base + c0] = (__bf16)v0; out[base + c1] = (__bf16)v1;
        s0 += v0; q0 += v0 * v0; s1 += v1; q1 += v1 * v1;
    }
    atomicAdd(&csum[c0], s0); atomicAdd(&csq[c0], q0);
    atomicAdd(&csum[c1], s1); atomicAdd(&csq[c1], q1);
}

// ---------------------------------------------------------------------------
// Final: out[b] = bnrelu(h1b)@Wout[0:256] + bnrelu(h2b)@Wout[256:512]
//               + gene[b,:]@Wres + b_out + b_res.   One wave per row.
// ---------------------------------------------------------------------------
__global__ __launch_bounds__(256) void final_kernel(
    const __bf16* __restrict__ h1, const __bf16* __restrict__ h2,
    const float* __restrict__ gene,
    const float* __restrict__ s1, const float* __restrict__ q1,
    const float* __restrict__ gm1, const float* __restrict__ bt1,
    const float* __restrict__ s2, const float* __restrict__ q2,
    const float* __restrict__ gm2, const float* __restrict__ bt2,
    const float* __restrict__ Wout, const float* __restrict__ bo,
    const float* __restrict__ Wres, const float* __restrict__ br,
    float* __restrict__ outp)
{
    int t = threadIdx.x, lane = t & 63, wv = t >> 6;
    int row = blockIdx.x * 4 + wv;
    const float invB = 1.f / (float)BATCH;
    float acc = 0.f;
#pragma unroll
    for (int ii = 0; ii < 4; ii++) {
        int c = lane + ii * 64;
        float mu  = s1[c] * invB;
        float var = q1[c] * invB - mu * mu;
        float sc  = gm1[c] * rsqrtf(var + EPSV);
        float v   = ((float)h1[(size_t)row * NH2 + c] - mu) * sc + bt1[c];
        acc += fmaxf(v, 0.f) * Wout[c];
        mu  = s2[c] * invB;
        var = q2[c] * invB - mu * mu;
        sc  = gm2[c] * rsqrtf(var + EPSV);
        v   = ((float)h2[(size_t)row * NH2 + c] - mu) * sc + bt2[c];
        acc += fmaxf(v, 0.f) * Wout[NH2 + c];
        acc += gene[(size_t)row * NGRP + c] * Wres[c];
    }
#pragma unroll
    for (int off = 32; off > 0; off >>= 1) acc += __shfl_down(acc, off, 64);
    if (lane == 0) outp[row] = acc + bo[0] + br[0];
}

extern "C" void kernel_launch(void* const* d_in, const int* in_sizes, int n_in,
                              void* d_out, int out_size, void* d_ws, size_t ws_size,
                              hipStream_t stream)
{
    (void)in_sizes; (void)n_in; (void)out_size; (void)ws_size;
    const float* x        = (const float*)d_in[0];
    // d_in[1] = seg: pattern is compile-time known, unused
    const float* wgene    = (const float*)d_in[2];
    const float* bgene    = (const float*)d_in[3];
    const float* W1g1     = (const float*)d_in[4];
    const float* b1g1     = (const float*)d_in[5];
    const float* W2g1     = (const float*)d_in[6];
    const float* b2g1     = (const float*)d_in[7];
    const float* W1g2     = (const float*)d_in[8];
    const float* b1g2     = (const float*)d_in[9];
    const float* W2g2     = (const float*)d_in[10];
    const float* b2g2     = (const float*)d_in[11];
    const float* gamma1g1 = (const float*)d_in[12];
    const float* beta1g1  = (const float*)d_in[13];
    const float* gamma2g1 = (const float*)d_in[14];
    const float* beta2g1  = (const float*)d_in[15];
    const float* gamma1g2 = (const float*)d_in[16];
    const float* beta1g2  = (const float*)d_in[17];
    const float* gamma2g2 = (const float*)d_in[18];
    const float* beta2g2  = (const float*)d_in[19];
    const float* Wout     = (const float*)d_in[20];
    const float* bout     = (const float*)d_in[21];
    const float* Wres     = (const float*)d_in[22];
    const float* bres     = (const float*)d_in[23];
    float* outp = (float*)d_out;

    // Workspace (16B-aligned chunks):
    char* p = (char*)d_ws;
    float*  gene  = (float*)p;            p += (size_t)BATCH * NGRP * 4;   // 8 MB
    __bf16* geneb = (__bf16*)p;           p += (size_t)BATCH * NGRP * 2;   // 4 MB
    __bf16* h1pre = (__bf16*)p;           p += (size_t)BATCH * NH1 * 2;    // 8 MB
    __bf16* bufA  = (__bf16*)p;           p += (size_t)BATCH * NH1 * 2;    // 8 MB
    __bf16* h1b   = (__bf16*)p;           p += (size_t)BATCH * NH2 * 2;    // 4 MB
    __bf16* h2b   = (__bf16*)p;           p += (size_t)BATCH * NH2 * 2;    // 4 MB
    __bf16* w1t   = (__bf16*)p;           p += (size_t)NH1 * 256 * 2;      // 256 KB (512 x 256)
    __bf16* w2at  = (__bf16*)p;           p += (size_t)NH2 * NH1 * 2;      // 256 KB (256 x 512)
    __bf16* w2bt  = (__bf16*)p;           p += (size_t)NH2 * NH1 * 2;      // 256 KB
    float*  st    = (float*)p;
    float* s1a = st;          float* q1a = st + 512;
    float* s1b = st + 1024;   float* q1b = st + 1536;
    float* s2a = st + 2048;   float* q2a = st + 2560;
    float* s2b = st + 3072;   float* q2b = st + 3584;

    hipMemsetAsync(st, 0, 4096 * sizeof(float), stream);

    // weight transposes (bf16, zero-padded K)
    transposeW<<<dim3(256 / 32, NH1 / 32), 256, 0, stream>>>(W1g1, w1t, NSPLIT, NH1, 256);
    transposeW<<<dim3(NH1 / 32, NH2 / 32), 256, 0, stream>>>(W2g1, w2at, NH1, NH2, NH1);
    transposeW<<<dim3(NH1 / 32, NH2 / 32), 256, 0, stream>>>(W2g2, w2bt, NH1, NH2, NH1);

    gene_kernel<<<BATCH, 256, 0, stream>>>(x, wgene, bgene, gene, geneb);

    // layer1 branch1: geneb[:, :256(pad)] @ w1t^T + b1g1 -> h1pre, stats s1a/q1a
    gemm_bf16<<<dim3(NH1 / 64, BATCH / 64), 256, 0, stream>>>(
        geneb, NGRP, 256, w1t, NH1, b1g1, h1pre, s1a, q1a,
        nullptr, nullptr, nullptr, nullptr);

    // layer1 branch2 (K=3): gene[:, 253:256] @ W1g2 + b1g2 -> bufA, stats s2a/q2a
    b2l1_kernel<<<BATCH / 16, 256, 0, stream>>>(gene, W1g2, b1g2, bufA, s2a, q2a);

    // layer2 branch1: bnrelu(h1pre) @ w2at^T + b2g1 -> h1b, stats s1b/q1b
    gemm_bf16<<<dim3(NH2 / 64, BATCH / 64), 256, 0, stream>>>(
        h1pre, NH1, NH1, w2at, NH2, b2g1, h1b, s1b, q1b,
        s1a, q1a, gamma1g1, beta1g1);

    // layer2 branch2: bnrelu(bufA) @ w2bt^T + b2g2 -> h2b, stats s2b/q2b
    gemm_bf16<<<dim3(NH2 / 64, BATCH / 64), 256, 0, stream>>>(
        bufA, NH1, NH1, w2bt, NH2, b2g2, h2b, s2b, q2b,
        s2a, q2a, gamma1g2, beta1g2);

    final_kernel<<<BATCH / 4, 256, 0, stream>>>(
        h1b, h2b, gene,
        s1b, q1b, gamma2g1, beta2g1,
        s2b, q2b, gamma2g2, beta2g2,
        Wout, bout, Wres, bres, outp);
}

// Round 3
// 299.883 us; speedup vs baseline: 1.6398x; 1.0750x over previous
//
#include <hip/hip_runtime.h>
#include <cstddef>

#define BATCH  8192
#define NFEAT  4096
#define NGRP   256
#define NSPLIT 253
#define NH1    512
#define NH2    256
#define EPSV   1e-5f

typedef __bf16 bf16_8 __attribute__((ext_vector_type(8)));
typedef float  f32x4  __attribute__((ext_vector_type(4)));

__constant__ int c_prefix[8] = {0,3,8,16,28,44,65,92};
__constant__ int c_gsize[8]  = {3,5,8,12,16,21,27,36};

// ---------------------------------------------------------------------------
// Kernel 1: gene[b,g] = relu(sum_{f in group g} x[b,f]*w[f] + bg[g])
// One block per row. LDS padded +8 floats per 128-feature block (stride 136,
// 136 % 32 == 8 -> spreads banks; old layout collapsed to 8 banks w/ one
// 16-way conflict). Reduction: 8 lanes per group + shfl, not serial-36.
// ---------------------------------------------------------------------------
__global__ __launch_bounds__(256) void gene_kernel(const float* __restrict__ x,
        const float* __restrict__ wg, const float* __restrict__ bg,
        float* __restrict__ gene, __bf16* __restrict__ geneb)
{
    __shared__ float prod[NFEAT + 32 * 8];   // padded: f -> f + (f>>7)*8
    __shared__ float gout[NGRP];
    int t = threadIdx.x;
    size_t row = blockIdx.x;
    const float4* xv = (const float4*)(x + row * NFEAT);
    const float4* wv = (const float4*)wg;
#pragma unroll
    for (int i = 0; i < 4; i++) {
        int idx = t + 256 * i;
        float4 a = xv[idx], w = wv[idx];
        float4 p; p.x = a.x*w.x; p.y = a.y*w.y; p.z = a.z*w.z; p.w = a.w*w.w;
        int f = idx * 4;
        *(float4*)&prod[f + ((f >> 7) << 3)] = p;
    }
    __syncthreads();
    // 8 lanes per group; 32 groups per pass; 8 passes.
    int sub = t & 7, gidx = t >> 3;          // gidx 0..31
    int gi  = gidx & 7, fbo = gidx >> 3;     // invariant across passes
    int pre = c_prefix[gi], len = c_gsize[gi];
#pragma unroll
    for (int s = 0; s < 8; s++) {
        int base = (4 * s + fbo) * 136 + pre;
        float v = 0.f;
        for (int j = sub; j < len; j += 8) v += prod[base + j];
        v += __shfl_down(v, 4, 8);
        v += __shfl_down(v, 2, 8);
        v += __shfl_down(v, 1, 8);
        if (sub == 0) gout[(s << 5) + gidx] = v;
    }
    __syncthreads();
    {
        float s = fmaxf(gout[t] + bg[t], 0.f);
        gene[row * NGRP + t]  = s;
        geneb[row * NGRP + t] = (__bf16)s;
    }
}

// ---------------------------------------------------------------------------
// Transpose + convert weights: dst[n][k] = (bf16)src[k][n], zero-pad k in [K,Kp)
// ---------------------------------------------------------------------------
__global__ __launch_bounds__(256) void transposeW(const float* __restrict__ src,
        __bf16* __restrict__ dst, int K, int N, int Kp)
{
    __shared__ float tile[32][33];
    int kt = blockIdx.x * 32, nt = blockIdx.y * 32;
    int tx = threadIdx.x & 31, ty = threadIdx.x >> 5;   // 32 x 8
    for (int r = ty; r < 32; r += 8) {
        int k = kt + r, n = nt + tx;
        tile[r][tx] = (k < K && n < N) ? src[(size_t)k * N + n] : 0.f;
    }
    __syncthreads();
    for (int r = ty; r < 32; r += 8) {
        int n = nt + r, k = kt + tx;
        if (n < N && k < Kp) dst[(size_t)n * Kp + k] = (__bf16)tile[tx][r];
    }
}

// ---------------------------------------------------------------------------
// GEMM1 (bf16 MFMA): C[M x N] = A[M x K] @ WT^T + bias, no BN on A.
// 64x64 tile, BK=64, 4 waves (2x2), wave=32x32 via mfma_f32_16x16x32_bf16.
//   A/B operand: [m|n = lane&15][k = (lane>>4)*8 + j]
//   C/D:         col = lane&15, row = (lane>>4)*4 + reg
// Fused per-column sum/sumsq into csum/csq.
// ---------------------------------------------------------------------------
__global__ __launch_bounds__(256) void gemm_bf16(
    const __bf16* __restrict__ A, int lda, int K,
    const __bf16* __restrict__ WT, int n_total,
    const float* __restrict__ bias,
    __bf16* __restrict__ C,
    float* __restrict__ csum, float* __restrict__ csq)
{
    __shared__ __align__(16) __bf16 As[64][72];
    __shared__ __align__(16) __bf16 Bs[64][72];
    __shared__ float sred[64];
    __shared__ float qred[64];

    int t = threadIdx.x;
    int n0 = blockIdx.x * 64;
    int m0 = blockIdx.y * 64;
    if (t < 64) { sred[t] = 0.f; qred[t] = 0.f; }

    int lane = t & 63, w = t >> 6;
    int wm = (w & 1) * 32, wn = (w >> 1) * 32;
    int fm = lane & 15, quad = lane >> 4;

    f32x4 acc[2][2];
#pragma unroll
    for (int i = 0; i < 2; i++)
#pragma unroll
        for (int j = 0; j < 2; j++) acc[i][j] = (f32x4){0.f, 0.f, 0.f, 0.f};

    int r0 = t >> 3;
    int kc = (t & 7) * 8;

    int nk = K >> 6;
    for (int kt = 0; kt < nk; kt++) {
        int kk = kt << 6;
        __syncthreads();
#pragma unroll
        for (int h = 0; h < 2; h++) {
            int row = r0 + h * 32;
            *(uint4*)&As[row][kc] = *(const uint4*)(A + (size_t)(m0 + row) * lda + kk + kc);
            *(uint4*)&Bs[row][kc] = *(const uint4*)(WT + (size_t)(n0 + row) * K + kk + kc);
        }
        __syncthreads();
#pragma unroll
        for (int kc2 = 0; kc2 < 64; kc2 += 32) {
            bf16_8 a0 = *(const bf16_8*)&As[wm + fm][kc2 + quad * 8];
            bf16_8 a1 = *(const bf16_8*)&As[wm + 16 + fm][kc2 + quad * 8];
            bf16_8 b0 = *(const bf16_8*)&Bs[wn + fm][kc2 + quad * 8];
            bf16_8 b1 = *(const bf16_8*)&Bs[wn + 16 + fm][kc2 + quad * 8];
            acc[0][0] = __builtin_amdgcn_mfma_f32_16x16x32_bf16(a0, b0, acc[0][0], 0, 0, 0);
            acc[0][1] = __builtin_amdgcn_mfma_f32_16x16x32_bf16(a0, b1, acc[0][1], 0, 0, 0);
            acc[1][0] = __builtin_amdgcn_mfma_f32_16x16x32_bf16(a1, b0, acc[1][0], 0, 0, 0);
            acc[1][1] = __builtin_amdgcn_mfma_f32_16x16x32_bf16(a1, b1, acc[1][1], 0, 0, 0);
        }
    }

    float myS[2] = {0.f, 0.f}, myQ[2] = {0.f, 0.f};
#pragma unroll
    for (int j = 0; j < 2; j++) {
        int col = n0 + wn + j * 16 + fm;
        float bv = bias[col];
#pragma unroll
        for (int i = 0; i < 2; i++)
#pragma unroll
            for (int r = 0; r < 4; r++) {
                float v = acc[i][j][r] + bv;
                int row = m0 + wm + i * 16 + quad * 4 + r;
                C[(size_t)row * n_total + col] = (__bf16)v;
                myS[j] += v; myQ[j] += v * v;
            }
    }
#pragma unroll
    for (int j = 0; j < 2; j++) {
        atomicAdd(&sred[wn + j * 16 + fm], myS[j]);
        atomicAdd(&qred[wn + j * 16 + fm], myQ[j]);
    }
    __syncthreads();
    if (t < 64) {
        atomicAdd(&csum[n0 + t], sred[t]);
        atomicAdd(&csq[n0 + t], qred[t]);
    }
}

// ---------------------------------------------------------------------------
// GEMM2 dual (both branches in one grid, blockIdx.z selects): K=512, N=256,
// BN+ReLU fused on A-load from batch stats. Same tile structure as gemm_bf16.
// ---------------------------------------------------------------------------
__global__ __launch_bounds__(256) void gemm2_dual(
    const __bf16* A0, const __bf16* A1,
    const __bf16* WT0, const __bf16* WT1,
    const float* bias0, const float* bias1,
    __bf16* C0, __bf16* C1,
    float* csum0, float* csq0, float* csum1, float* csq1,
    const float* as0, const float* aq0, const float* ag0, const float* ab0,
    const float* as1, const float* aq1, const float* ag1, const float* ab1)
{
    const int K = NH1, n_total = NH2;
    __shared__ __align__(16) __bf16 As[64][72];
    __shared__ __align__(16) __bf16 Bs[64][72];
    __shared__ float bnsc[NH1];
    __shared__ float bnsh[NH1];
    __shared__ float sred[64];
    __shared__ float qred[64];

    int z = blockIdx.z;
    const __bf16* A    = z ? A1 : A0;
    const __bf16* WT   = z ? WT1 : WT0;
    const float*  bias = z ? bias1 : bias0;
    __bf16*       C    = z ? C1 : C0;
    float* csum = z ? csum1 : csum0;
    float* csq  = z ? csq1  : csq0;
    const float* a_sum = z ? as1 : as0;
    const float* a_sq  = z ? aq1 : aq0;
    const float* a_g   = z ? ag1 : ag0;
    const float* a_b   = z ? ab1 : ab0;

    int t = threadIdx.x;
    int n0 = blockIdx.x * 64;
    int m0 = blockIdx.y * 64;
    {
        const float invB = 1.f / (float)BATCH;
        for (int k = t; k < K; k += 256) {
            float mu  = a_sum[k] * invB;
            float var = a_sq[k] * invB - mu * mu;
            float sc  = a_g[k] * rsqrtf(var + EPSV);
            bnsc[k] = sc;
            bnsh[k] = a_b[k] - mu * sc;
        }
    }
    if (t < 64) { sred[t] = 0.f; qred[t] = 0.f; }

    int lane = t & 63, w = t >> 6;
    int wm = (w & 1) * 32, wn = (w >> 1) * 32;
    int fm = lane & 15, quad = lane >> 4;

    f32x4 acc[2][2];
#pragma unroll
    for (int i = 0; i < 2; i++)
#pragma unroll
        for (int j = 0; j < 2; j++) acc[i][j] = (f32x4){0.f, 0.f, 0.f, 0.f};

    int r0 = t >> 3;
    int kc = (t & 7) * 8;

    for (int kt = 0; kt < (K >> 6); kt++) {
        int kk = kt << 6;
        __syncthreads();
#pragma unroll
        for (int h = 0; h < 2; h++) {
            int row = r0 + h * 32;
            uint4 raw = *(const uint4*)(A + (size_t)(m0 + row) * K + kk + kc);
            __bf16 vals[8];
#pragma unroll
            for (int c = 0; c < 4; c++) {
                unsigned uu = (&raw.x)[c];
                int kg = kk + kc + 2 * c;
                float flo = __uint_as_float(uu << 16);
                float fhi = __uint_as_float(uu & 0xffff0000u);
                flo = fmaxf(fmaf(flo, bnsc[kg],     bnsh[kg]),     0.f);
                fhi = fmaxf(fmaf(fhi, bnsc[kg + 1], bnsh[kg + 1]), 0.f);
                vals[2 * c]     = (__bf16)flo;
                vals[2 * c + 1] = (__bf16)fhi;
            }
            *(bf16_8*)&As[row][kc] = *(bf16_8*)vals;
            *(uint4*)&Bs[row][kc] = *(const uint4*)(WT + (size_t)(n0 + row) * K + kk + kc);
        }
        __syncthreads();
#pragma unroll
        for (int kc2 = 0; kc2 < 64; kc2 += 32) {
            bf16_8 a0 = *(const bf16_8*)&As[wm + fm][kc2 + quad * 8];
            bf16_8 a1 = *(const bf16_8*)&As[wm + 16 + fm][kc2 + quad * 8];
            bf16_8 b0 = *(const bf16_8*)&Bs[wn + fm][kc2 + quad * 8];
            bf16_8 b1 = *(const bf16_8*)&Bs[wn + 16 + fm][kc2 + quad * 8];
            acc[0][0] = __builtin_amdgcn_mfma_f32_16x16x32_bf16(a0, b0, acc[0][0], 0, 0, 0);
            acc[0][1] = __builtin_amdgcn_mfma_f32_16x16x32_bf16(a0, b1, acc[0][1], 0, 0, 0);
            acc[1][0] = __builtin_amdgcn_mfma_f32_16x16x32_bf16(a1, b0, acc[1][0], 0, 0, 0);
            acc[1][1] = __builtin_amdgcn_mfma_f32_16x16x32_bf16(a1, b1, acc[1][1], 0, 0, 0);
        }
    }

    float myS[2] = {0.f, 0.f}, myQ[2] = {0.f, 0.f};
#pragma unroll
    for (int j = 0; j < 2; j++) {
        int col = n0 + wn + j * 16 + fm;
        float bv = bias[col];
#pragma unroll
        for (int i = 0; i < 2; i++)
#pragma unroll
            for (int r = 0; r < 4; r++) {
                float v = acc[i][j][r] + bv;
                int row = m0 + wm + i * 16 + quad * 4 + r;
                C[(size_t)row * n_total + col] = (__bf16)v;
                myS[j] += v; myQ[j] += v * v;
            }
    }
#pragma unroll
    for (int j = 0; j < 2; j++) {
        atomicAdd(&sred[wn + j * 16 + fm], myS[j]);
        atomicAdd(&qred[wn + j * 16 + fm], myQ[j]);
    }
    __syncthreads();
    if (t < 64) {
        atomicAdd(&csum[n0 + t], sred[t]);
        atomicAdd(&csq[n0 + t], qred[t]);
    }
}

// ---------------------------------------------------------------------------
// Branch 2 layer 1: out[b,:] = g2[b,0:3] @ W1g2[3,512] + b1g2, K=3. bf16 out.
// 64 rows per block (128 blocks) -> 4x fewer global stat atomics.
// ---------------------------------------------------------------------------
__global__ __launch_bounds__(256) void b2l1_kernel(const float* __restrict__ gene,
    const float* __restrict__ W, const float* __restrict__ bias,
    __bf16* __restrict__ out, float* __restrict__ csum, float* __restrict__ csq)
{
    __shared__ float Ws[3 * 512];
    __shared__ float bsh[512];
    __shared__ float gv[64][3];
    int t = threadIdx.x;
    for (int i = t; i < 1536; i += 256) Ws[i] = W[i];
    for (int i = t; i < 512; i += 256) bsh[i] = bias[i];
    int row0 = blockIdx.x * 64;
    if (t < 192) gv[t / 3][t % 3] = gene[(size_t)(row0 + t / 3) * NGRP + NSPLIT + (t % 3)];
    __syncthreads();
    int c0 = t, c1 = t + 256;
    float s0 = 0, q0 = 0, s1 = 0, q1 = 0;
    for (int r = 0; r < 64; r++) {
        float a = gv[r][0], b = gv[r][1], c = gv[r][2];
        float v0 = bsh[c0] + a * Ws[c0] + b * Ws[512 + c0] + c * Ws[1024 + c0];
        float v1 = bsh[c1] + a * Ws[c1] + b * Ws[512 + c1] + c * Ws[1024 + c1];
        size_t base = (size_t)(row0 + r) * NH1;
        out[base + c0] = (__bf16)v0; out[base + c1] = (__bf16)v1;
        s0 += v0; q0 += v0 * v0; s1 += v1; q1 += v1 * v1;
    }
    atomicAdd(&csum[c0], s0); atomicAdd(&csq[c0], q0);
    atomicAdd(&csum[c1], s1); atomicAdd(&csq[c1], q1);
}

// ---------------------------------------------------------------------------
// Final: out[b] = bnrelu(h1b)@Wout[0:256] + bnrelu(h2b)@Wout[256:512]
//               + gene[b,:]@Wres + b_out + b_res.  One wave per row, 4 cols/lane.
// ---------------------------------------------------------------------------
__global__ __launch_bounds__(256) void final_kernel(
    const __bf16* __restrict__ h1, const __bf16* __restrict__ h2,
    const float* __restrict__ gene,
    const float* __restrict__ s1, const float* __restrict__ q1,
    const float* __restrict__ gm1, const float* __restrict__ bt1,
    const float* __restrict__ s2, const float* __restrict__ q2,
    const float* __restrict__ gm2, const float* __restrict__ bt2,
    const float* __restrict__ Wout, const float* __restrict__ bo,
    const float* __restrict__ Wres, const float* __restrict__ br,
    float* __restrict__ outp)
{
    int t = threadIdx.x, lane = t & 63, wv = t >> 6;
    int row = blockIdx.x * 4 + wv;
    int c = lane * 4;
    const float invB = 1.f / (float)BATCH;
    float4 vs1 = *(const float4*)&s1[c],  vq1 = *(const float4*)&q1[c];
    float4 vg1 = *(const float4*)&gm1[c], vb1 = *(const float4*)&bt1[c];
    float4 vs2 = *(const float4*)&s2[c],  vq2 = *(const float4*)&q2[c];
    float4 vg2 = *(const float4*)&gm2[c], vb2 = *(const float4*)&bt2[c];
    float4 wo1 = *(const float4*)&Wout[c];
    float4 wo2 = *(const float4*)&Wout[NH2 + c];
    float4 wr  = *(const float4*)&Wres[c];
    ushort4 u1 = *(const ushort4*)((const unsigned short*)h1 + (size_t)row * NH2 + c);
    ushort4 u2 = *(const ushort4*)((const unsigned short*)h2 + (size_t)row * NH2 + c);
    float4 gv  = *(const float4*)&gene[(size_t)row * NGRP + c];
    float acc = 0.f;
#pragma unroll
    for (int e = 0; e < 4; e++) {
        float h1f = __uint_as_float((unsigned)(&u1.x)[e] << 16);
        float h2f = __uint_as_float((unsigned)(&u2.x)[e] << 16);
        float mu  = (&vs1.x)[e] * invB;
        float var = (&vq1.x)[e] * invB - mu * mu;
        float v   = (h1f - mu) * (&vg1.x)[e] * rsqrtf(var + EPSV) + (&vb1.x)[e];
        acc += fmaxf(v, 0.f) * (&wo1.x)[e];
        mu  = (&vs2.x)[e] * invB;
        var = (&vq2.x)[e] * invB - mu * mu;
        v   = (h2f - mu) * (&vg2.x)[e] * rsqrtf(var + EPSV) + (&vb2.x)[e];
        acc += fmaxf(v, 0.f) * (&wo2.x)[e];
        acc += (&gv.x)[e] * (&wr.x)[e];
    }
#pragma unroll
    for (int off = 32; off > 0; off >>= 1) acc += __shfl_down(acc, off, 64);
    if (lane == 0) outp[row] = acc + bo[0] + br[0];
}

extern "C" void kernel_launch(void* const* d_in, const int* in_sizes, int n_in,
                              void* d_out, int out_size, void* d_ws, size_t ws_size,
                              hipStream_t stream)
{
    (void)in_sizes; (void)n_in; (void)out_size; (void)ws_size;
    const float* x        = (const float*)d_in[0];
    const float* wgene    = (const float*)d_in[2];
    const float* bgene    = (const float*)d_in[3];
    const float* W1g1     = (const float*)d_in[4];
    const float* b1g1     = (const float*)d_in[5];
    const float* W2g1     = (const float*)d_in[6];
    const float* b2g1     = (const float*)d_in[7];
    const float* W1g2     = (const float*)d_in[8];
    const float* b1g2     = (const float*)d_in[9];
    const float* W2g2     = (const float*)d_in[10];
    const float* b2g2     = (const float*)d_in[11];
    const float* gamma1g1 = (const float*)d_in[12];
    const float* beta1g1  = (const float*)d_in[13];
    const float* gamma2g1 = (const float*)d_in[14];
    const float* beta2g1  = (const float*)d_in[15];
    const float* gamma1g2 = (const float*)d_in[16];
    const float* beta1g2  = (const float*)d_in[17];
    const float* gamma2g2 = (const float*)d_in[18];
    const float* beta2g2  = (const float*)d_in[19];
    const float* Wout     = (const float*)d_in[20];
    const float* bout     = (const float*)d_in[21];
    const float* Wres     = (const float*)d_in[22];
    const float* bres     = (const float*)d_in[23];
    float* outp = (float*)d_out;

    char* p = (char*)d_ws;
    float*  gene  = (float*)p;            p += (size_t)BATCH * NGRP * 4;
    __bf16* geneb = (__bf16*)p;           p += (size_t)BATCH * NGRP * 2;
    __bf16* h1pre = (__bf16*)p;           p += (size_t)BATCH * NH1 * 2;
    __bf16* bufA  = (__bf16*)p;           p += (size_t)BATCH * NH1 * 2;
    __bf16* h1b   = (__bf16*)p;           p += (size_t)BATCH * NH2 * 2;
    __bf16* h2b   = (__bf16*)p;           p += (size_t)BATCH * NH2 * 2;
    __bf16* w1t   = (__bf16*)p;           p += (size_t)NH1 * 256 * 2;
    __bf16* w2at  = (__bf16*)p;           p += (size_t)NH2 * NH1 * 2;
    __bf16* w2bt  = (__bf16*)p;           p += (size_t)NH2 * NH1 * 2;
    float*  st    = (float*)p;
    float* s1a = st;          float* q1a = st + 512;
    float* s1b = st + 1024;   float* q1b = st + 1536;
    float* s2a = st + 2048;   float* q2a = st + 2560;
    float* s2b = st + 3072;   float* q2b = st + 3584;

    hipMemsetAsync(st, 0, 4096 * sizeof(float), stream);

    transposeW<<<dim3(256 / 32, NH1 / 32), 256, 0, stream>>>(W1g1, w1t, NSPLIT, NH1, 256);
    transposeW<<<dim3(NH1 / 32, NH2 / 32), 256, 0, stream>>>(W2g1, w2at, NH1, NH2, NH1);
    transposeW<<<dim3(NH1 / 32, NH2 / 32), 256, 0, stream>>>(W2g2, w2bt, NH1, NH2, NH1);

    gene_kernel<<<BATCH, 256, 0, stream>>>(x, wgene, bgene, gene, geneb);

    // layer1 branch1: geneb[:, :256(pad)] @ w1t^T + b1g1 -> h1pre, stats s1a/q1a
    gemm_bf16<<<dim3(NH1 / 64, BATCH / 64), 256, 0, stream>>>(
        geneb, NGRP, 256, w1t, NH1, b1g1, h1pre, s1a, q1a);

    // layer1 branch2 (K=3): gene[:, 253:256] @ W1g2 + b1g2 -> bufA, stats s2a/q2a
    b2l1_kernel<<<BATCH / 64, 256, 0, stream>>>(gene, W1g2, b1g2, bufA, s2a, q2a);

    // layer2 both branches: bnrelu(A) @ WT^T + bias -> h1b/h2b, stats
    gemm2_dual<<<dim3(NH2 / 64, BATCH / 64, 2), 256, 0, stream>>>(
        h1pre, bufA, w2at, w2bt, b2g1, b2g2, h1b, h2b,
        s1b, q1b, s2b, q2b,
        s1a, q1a, gamma1g1, beta1g1,
        s2a, q2a, gamma1g2, beta1g2);

    final_kernel<<<BATCH / 4, 256, 0, stream>>>(
        h1b, h2b, gene,
        s1b, q1b, gamma2g1, beta2g1,
        s2b, q2b, gamma2g2, beta2g2,
        Wout, bout, Wres, bres, outp);
}

// Round 4
// 277.395 us; speedup vs baseline: 1.7727x; 1.0811x over previous
//
#include <hip/hip_runtime.h>
#include <cstddef>

#define BATCH  8192
#define NFEAT  4096
#define NGRP   256
#define NSPLIT 253
#define NH1    512
#define NH2    256
#define EPSV   1e-5f

typedef __bf16 bf16_8 __attribute__((ext_vector_type(8)));
typedef float  f32x4  __attribute__((ext_vector_type(4)));

__constant__ int c_prefix[8] = {0,3,8,16,28,44,65,92};
__constant__ int c_gsize[8]  = {3,5,8,12,16,21,27,36};

// ---------------------------------------------------------------------------
// Kernel 1: geneb[b,g] = (bf16) relu(sum_{f in group g} x[b,f]*w[f] + bg[g])
// One block per row. LDS padded +8 floats per 128-feature block (stride 136).
// Reduction: 8 lanes per group + shfl.
// ---------------------------------------------------------------------------
__global__ __launch_bounds__(256) void gene_kernel(const float* __restrict__ x,
        const float* __restrict__ wg, const float* __restrict__ bg,
        __bf16* __restrict__ geneb)
{
    __shared__ float prod[NFEAT + 32 * 8];   // padded: f -> f + (f>>7)*8
    __shared__ float gout[NGRP];
    int t = threadIdx.x;
    size_t row = blockIdx.x;
    const float4* xv = (const float4*)(x + row * NFEAT);
    const float4* wv = (const float4*)wg;
#pragma unroll
    for (int i = 0; i < 4; i++) {
        int idx = t + 256 * i;
        float4 a = xv[idx], w = wv[idx];
        float4 p; p.x = a.x*w.x; p.y = a.y*w.y; p.z = a.z*w.z; p.w = a.w*w.w;
        int f = idx * 4;
        *(float4*)&prod[f + ((f >> 7) << 3)] = p;
    }
    __syncthreads();
    int sub = t & 7, gidx = t >> 3;
    int gi  = gidx & 7, fbo = gidx >> 3;
    int pre = c_prefix[gi], len = c_gsize[gi];
#pragma unroll
    for (int s = 0; s < 8; s++) {
        int base = (4 * s + fbo) * 136 + pre;
        float v = 0.f;
        for (int j = sub; j < len; j += 8) v += prod[base + j];
        v += __shfl_down(v, 4, 8);
        v += __shfl_down(v, 2, 8);
        v += __shfl_down(v, 1, 8);
        if (sub == 0) gout[(s << 5) + gidx] = v;
    }
    __syncthreads();
    geneb[row * NGRP + t] = (__bf16)fmaxf(gout[t] + bg[t], 0.f);
}

// ---------------------------------------------------------------------------
// All three weight transposes in one launch (z selects). dst[n][k]=(bf16)src[k][n],
// zero-pad k in [K,Kp).
// ---------------------------------------------------------------------------
__global__ __launch_bounds__(256) void transpose_all(
        const float* __restrict__ W1g1, const float* __restrict__ W2g1,
        const float* __restrict__ W2g2,
        __bf16* __restrict__ w1t, __bf16* __restrict__ w2at, __bf16* __restrict__ w2bt)
{
    __shared__ float tile[32][33];
    int z = blockIdx.z;
    const float* src; __bf16* dst; int K, N, Kp;
    if (z == 0)      { src = W1g1; dst = w1t;  K = NSPLIT; N = NH1; Kp = 256; }
    else if (z == 1) { src = W2g1; dst = w2at; K = NH1;    N = NH2; Kp = NH1; }
    else             { src = W2g2; dst = w2bt; K = NH1;    N = NH2; Kp = NH1; }
    int ktiles = (K + 31) >> 5, ntiles = N >> 5;
    int tid = blockIdx.y * 16 + blockIdx.x;
    if (tid >= ktiles * ntiles) return;
    int kt = (tid % ktiles) * 32, nt = (tid / ktiles) * 32;
    int tx = threadIdx.x & 31, ty = threadIdx.x >> 5;
    for (int r = ty; r < 32; r += 8) {
        int k = kt + r, n = nt + tx;
        tile[r][tx] = (k < K && n < N) ? src[(size_t)k * N + n] : 0.f;
    }
    __syncthreads();
    for (int r = ty; r < 32; r += 8) {
        int n = nt + r, k = kt + tx;
        if (n < N && k < Kp) dst[(size_t)n * Kp + k] = (__bf16)tile[tx][r];
    }
}

// ---------------------------------------------------------------------------
// GEMM1 + fused b2l1: grid (9, 128). x<8: 64x64 MFMA tile of
// h1pre = geneb @ w1t^T + b1g1 (stats s1a/q1a). x==8: b2l1 for 64 rows:
// bufA = geneb[:,253:256] @ W1g2 + b1g2 (stats s2a/q2a).
// Shared LDS aliased through one char buffer.
// ---------------------------------------------------------------------------
__global__ __launch_bounds__(256) void gemm1_fused(
    const __bf16* __restrict__ geneb, const __bf16* __restrict__ w1t,
    const float* __restrict__ b1g1, __bf16* __restrict__ h1pre,
    float* __restrict__ s1a, float* __restrict__ q1a,
    const float* __restrict__ W1g2, const float* __restrict__ b1g2,
    __bf16* __restrict__ bufA, float* __restrict__ s2a, float* __restrict__ q2a)
{
    __shared__ __align__(16) char smem[19456];
    int t = threadIdx.x;

    if (blockIdx.x == 8) {
        // ---------------- b2l1 path (K=3) ----------------
        float* Ws  = (float*)smem;        // 1536
        float* bsh = Ws + 1536;           // 512
        float* gv  = bsh + 512;           // 192
        for (int i = t; i < 1536; i += 256) Ws[i] = W1g2[i];
        for (int i = t; i < 512; i += 256) bsh[i] = b1g2[i];
        int row0 = blockIdx.y * 64;
        if (t < 192)
            gv[t] = (float)geneb[(size_t)(row0 + t / 3) * NGRP + NSPLIT + (t % 3)];
        __syncthreads();
        int c0 = t, c1 = t + 256;
        float s0 = 0, q0 = 0, s1 = 0, q1 = 0;
        for (int r = 0; r < 64; r++) {
            float a = gv[3 * r], b = gv[3 * r + 1], c = gv[3 * r + 2];
            float v0 = bsh[c0] + a * Ws[c0] + b * Ws[512 + c0] + c * Ws[1024 + c0];
            float v1 = bsh[c1] + a * Ws[c1] + b * Ws[512 + c1] + c * Ws[1024 + c1];
            size_t base = (size_t)(row0 + r) * NH1;
            bufA[base + c0] = (__bf16)v0; bufA[base + c1] = (__bf16)v1;
            s0 += v0; q0 += v0 * v0; s1 += v1; q1 += v1 * v1;
        }
        atomicAdd(&s2a[c0], s0); atomicAdd(&q2a[c0], q0);
        atomicAdd(&s2a[c1], s1); atomicAdd(&q2a[c1], q1);
        return;
    }

    // ---------------- MFMA GEMM path ----------------
    const int K = 256;           // padded K (253 + 3 zero rows of w1t)
    __bf16 (*As)[72] = (__bf16(*)[72])smem;            // 9216 B
    __bf16 (*Bs)[72] = (__bf16(*)[72])(smem + 9216);   // 9216 B
    float* sred = (float*)(smem + 18432);              // 256 B
    float* qred = sred + 64;                           // 256 B

    int n0 = blockIdx.x * 64;
    int m0 = blockIdx.y * 64;
    if (t < 64) { sred[t] = 0.f; qred[t] = 0.f; }

    int lane = t & 63, w = t >> 6;
    int wm = (w & 1) * 32, wn = (w >> 1) * 32;
    int fm = lane & 15, quad = lane >> 4;

    f32x4 acc[2][2];
#pragma unroll
    for (int i = 0; i < 2; i++)
#pragma unroll
        for (int j = 0; j < 2; j++) acc[i][j] = (f32x4){0.f, 0.f, 0.f, 0.f};

    int r0 = t >> 3;
    int kc = (t & 7) * 8;

    for (int kt = 0; kt < (K >> 6); kt++) {
        int kk = kt << 6;
        __syncthreads();
#pragma unroll
        for (int h = 0; h < 2; h++) {
            int row = r0 + h * 32;
            *(uint4*)&As[row][kc] = *(const uint4*)(geneb + (size_t)(m0 + row) * NGRP + kk + kc);
            *(uint4*)&Bs[row][kc] = *(const uint4*)(w1t + (size_t)(n0 + row) * K + kk + kc);
        }
        __syncthreads();
#pragma unroll
        for (int kc2 = 0; kc2 < 64; kc2 += 32) {
            bf16_8 a0 = *(const bf16_8*)&As[wm + fm][kc2 + quad * 8];
            bf16_8 a1 = *(const bf16_8*)&As[wm + 16 + fm][kc2 + quad * 8];
            bf16_8 b0 = *(const bf16_8*)&Bs[wn + fm][kc2 + quad * 8];
            bf16_8 b1 = *(const bf16_8*)&Bs[wn + 16 + fm][kc2 + quad * 8];
            acc[0][0] = __builtin_amdgcn_mfma_f32_16x16x32_bf16(a0, b0, acc[0][0], 0, 0, 0);
            acc[0][1] = __builtin_amdgcn_mfma_f32_16x16x32_bf16(a0, b1, acc[0][1], 0, 0, 0);
            acc[1][0] = __builtin_amdgcn_mfma_f32_16x16x32_bf16(a1, b0, acc[1][0], 0, 0, 0);
            acc[1][1] = __builtin_amdgcn_mfma_f32_16x16x32_bf16(a1, b1, acc[1][1], 0, 0, 0);
        }
    }

    float myS[2] = {0.f, 0.f}, myQ[2] = {0.f, 0.f};
#pragma unroll
    for (int j = 0; j < 2; j++) {
        int col = n0 + wn + j * 16 + fm;
        float bv = b1g1[col];
#pragma unroll
        for (int i = 0; i < 2; i++)
#pragma unroll
            for (int r = 0; r < 4; r++) {
                float v = acc[i][j][r] + bv;
                int row = m0 + wm + i * 16 + quad * 4 + r;
                h1pre[(size_t)row * NH1 + col] = (__bf16)v;
                myS[j] += v; myQ[j] += v * v;
            }
    }
#pragma unroll
    for (int j = 0; j < 2; j++) {
        atomicAdd(&sred[wn + j * 16 + fm], myS[j]);
        atomicAdd(&qred[wn + j * 16 + fm], myQ[j]);
    }
    __syncthreads();
    if (t < 64) {
        atomicAdd(&s1a[n0 + t], sred[t]);
        atomicAdd(&q1a[n0 + t], qred[t]);
    }
}

// ---------------------------------------------------------------------------
// GEMM2 dual (both branches, blockIdx.z selects): K=512, N=256, BN+ReLU fused
// on A-load from batch stats.
// ---------------------------------------------------------------------------
__global__ __launch_bounds__(256) void gemm2_dual(
    const __bf16* A0, const __bf16* A1,
    const __bf16* WT0, const __bf16* WT1,
    const float* bias0, const float* bias1,
    __bf16* C0, __bf16* C1,
    float* csum0, float* csq0, float* csum1, float* csq1,
    const float* as0, const float* aq0, const float* ag0, const float* ab0,
    const float* as1, const float* aq1, const float* ag1, const float* ab1)
{
    const int K = NH1, n_total = NH2;
    __shared__ __align__(16) __bf16 As[64][72];
    __shared__ __align__(16) __bf16 Bs[64][72];
    __shared__ float bnsc[NH1];
    __shared__ float bnsh[NH1];
    __shared__ float sred[64];
    __shared__ float qred[64];

    int z = blockIdx.z;
    const __bf16* A    = z ? A1 : A0;
    const __bf16* WT   = z ? WT1 : WT0;
    const float*  bias = z ? bias1 : bias0;
    __bf16*       C    = z ? C1 : C0;
    float* csum = z ? csum1 : csum0;
    float* csq  = z ? csq1  : csq0;
    const float* a_sum = z ? as1 : as0;
    const float* a_sq  = z ? aq1 : aq0;
    const float* a_g   = z ? ag1 : ag0;
    const float* a_b   = z ? ab1 : ab0;

    int t = threadIdx.x;
    int n0 = blockIdx.x * 64;
    int m0 = blockIdx.y * 64;
    {
        const float invB = 1.f / (float)BATCH;
        for (int k = t; k < K; k += 256) {
            float mu  = a_sum[k] * invB;
            float var = a_sq[k] * invB - mu * mu;
            float sc  = a_g[k] * rsqrtf(var + EPSV);
            bnsc[k] = sc;
            bnsh[k] = a_b[k] - mu * sc;
        }
    }
    if (t < 64) { sred[t] = 0.f; qred[t] = 0.f; }

    int lane = t & 63, w = t >> 6;
    int wm = (w & 1) * 32, wn = (w >> 1) * 32;
    int fm = lane & 15, quad = lane >> 4;

    f32x4 acc[2][2];
#pragma unroll
    for (int i = 0; i < 2; i++)
#pragma unroll
        for (int j = 0; j < 2; j++) acc[i][j] = (f32x4){0.f, 0.f, 0.f, 0.f};

    int r0 = t >> 3;
    int kc = (t & 7) * 8;

    for (int kt = 0; kt < (K >> 6); kt++) {
        int kk = kt << 6;
        __syncthreads();
#pragma unroll
        for (int h = 0; h < 2; h++) {
            int row = r0 + h * 32;
            uint4 raw = *(const uint4*)(A + (size_t)(m0 + row) * K + kk + kc);
            __bf16 vals[8];
#pragma unroll
            for (int c = 0; c < 4; c++) {
                unsigned uu = (&raw.x)[c];
                int kg = kk + kc + 2 * c;
                float flo = __uint_as_float(uu << 16);
                float fhi = __uint_as_float(uu & 0xffff0000u);
                flo = fmaxf(fmaf(flo, bnsc[kg],     bnsh[kg]),     0.f);
                fhi = fmaxf(fmaf(fhi, bnsc[kg + 1], bnsh[kg + 1]), 0.f);
                vals[2 * c]     = (__bf16)flo;
                vals[2 * c + 1] = (__bf16)fhi;
            }
            *(bf16_8*)&As[row][kc] = *(bf16_8*)vals;
            *(uint4*)&Bs[row][kc] = *(const uint4*)(WT + (size_t)(n0 + row) * K + kk + kc);
        }
        __syncthreads();
#pragma unroll
        for (int kc2 = 0; kc2 < 64; kc2 += 32) {
            bf16_8 a0 = *(const bf16_8*)&As[wm + fm][kc2 + quad * 8];
            bf16_8 a1 = *(const bf16_8*)&As[wm + 16 + fm][kc2 + quad * 8];
            bf16_8 b0 = *(const bf16_8*)&Bs[wn + fm][kc2 + quad * 8];
            bf16_8 b1 = *(const bf16_8*)&Bs[wn + 16 + fm][kc2 + quad * 8];
            acc[0][0] = __builtin_amdgcn_mfma_f32_16x16x32_bf16(a0, b0, acc[0][0], 0, 0, 0);
            acc[0][1] = __builtin_amdgcn_mfma_f32_16x16x32_bf16(a0, b1, acc[0][1], 0, 0, 0);
            acc[1][0] = __builtin_amdgcn_mfma_f32_16x16x32_bf16(a1, b0, acc[1][0], 0, 0, 0);
            acc[1][1] = __builtin_amdgcn_mfma_f32_16x16x32_bf16(a1, b1, acc[1][1], 0, 0, 0);
        }
    }

    float myS[2] = {0.f, 0.f}, myQ[2] = {0.f, 0.f};
#pragma unroll
    for (int j = 0; j < 2; j++) {
        int col = n0 + wn + j * 16 + fm;
        float bv = bias[col];
#pragma unroll
        for (int i = 0; i < 2; i++)
#pragma unroll
            for (int r = 0; r < 4; r++) {
                float v = acc[i][j][r] + bv;
                int row = m0 + wm + i * 16 + quad * 4 + r;
                C[(size_t)row * n_total + col] = (__bf16)v;
                myS[j] += v; myQ[j] += v * v;
            }
    }
#pragma unroll
    for (int j = 0; j < 2; j++) {
        atomicAdd(&sred[wn + j * 16 + fm], myS[j]);
        atomicAdd(&qred[wn + j * 16 + fm], myQ[j]);
    }
    __syncthreads();
    if (t < 64) {
        atomicAdd(&csum[n0 + t], sred[t]);
        atomicAdd(&csq[n0 + t], qred[t]);
    }
}

// ---------------------------------------------------------------------------
// Final: out[b] = bnrelu(h1b)@Wout[0:256] + bnrelu(h2b)@Wout[256:512]
//               + geneb[b,:]@Wres + b_out + b_res.  One wave per row, 4 cols/lane.
// ---------------------------------------------------------------------------
__global__ __launch_bounds__(256) void final_kernel(
    const __bf16* __restrict__ h1, const __bf16* __restrict__ h2,
    const __bf16* __restrict__ geneb,
    const float* __restrict__ s1, const float* __restrict__ q1,
    const float* __restrict__ gm1, const float* __restrict__ bt1,
    const float* __restrict__ s2, const float* __restrict__ q2,
    const float* __restrict__ gm2, const float* __restrict__ bt2,
    const float* __restrict__ Wout, const float* __restrict__ bo,
    const float* __restrict__ Wres, const float* __restrict__ br,
    float* __restrict__ outp)
{
    int t = threadIdx.x, lane = t & 63, wv = t >> 6;
    int row = blockIdx.x * 4 + wv;
    int c = lane * 4;
    const float invB = 1.f / (float)BATCH;
    float4 vs1 = *(const float4*)&s1[c],  vq1 = *(const float4*)&q1[c];
    float4 vg1 = *(const float4*)&gm1[c], vb1 = *(const float4*)&bt1[c];
    float4 vs2 = *(const float4*)&s2[c],  vq2 = *(const float4*)&q2[c];
    float4 vg2 = *(const float4*)&gm2[c], vb2 = *(const float4*)&bt2[c];
    float4 wo1 = *(const float4*)&Wout[c];
    float4 wo2 = *(const float4*)&Wout[NH2 + c];
    float4 wr  = *(const float4*)&Wres[c];
    ushort4 u1 = *(const ushort4*)((const unsigned short*)h1 + (size_t)row * NH2 + c);
    ushort4 u2 = *(const ushort4*)((const unsigned short*)h2 + (size_t)row * NH2 + c);
    ushort4 ug = *(const ushort4*)((const unsigned short*)geneb + (size_t)row * NGRP + c);
    float acc = 0.f;
#pragma unroll
    for (int e = 0; e < 4; e++) {
        float h1f = __uint_as_float((unsigned)(&u1.x)[e] << 16);
        float h2f = __uint_as_float((unsigned)(&u2.x)[e] << 16);
        float gvf = __uint_as_float((unsigned)(&ug.x)[e] << 16);
        float mu  = (&vs1.x)[e] * invB;
        float var = (&vq1.x)[e] * invB - mu * mu;
        float v   = (h1f - mu) * (&vg1.x)[e] * rsqrtf(var + EPSV) + (&vb1.x)[e];
        acc += fmaxf(v, 0.f) * (&wo1.x)[e];
        mu  = (&vs2.x)[e] * invB;
        var = (&vq2.x)[e] * invB - mu * mu;
        v   = (h2f - mu) * (&vg2.x)[e] * rsqrtf(var + EPSV) + (&vb2.x)[e];
        acc += fmaxf(v, 0.f) * (&wo2.x)[e];
        acc += gvf * (&wr.x)[e];
    }
#pragma unroll
    for (int off = 32; off > 0; off >>= 1) acc += __shfl_down(acc, off, 64);
    if (lane == 0) outp[row] = acc + bo[0] + br[0];
}

extern "C" void kernel_launch(void* const* d_in, const int* in_sizes, int n_in,
                              void* d_out, int out_size, void* d_ws, size_t ws_size,
                              hipStream_t stream)
{
    (void)in_sizes; (void)n_in; (void)out_size; (void)ws_size;
    const float* x        = (const float*)d_in[0];
    const float* wgene    = (const float*)d_in[2];
    const float* bgene    = (const float*)d_in[3];
    const float* W1g1     = (const float*)d_in[4];
    const float* b1g1     = (const float*)d_in[5];
    const float* W2g1     = (const float*)d_in[6];
    const float* b2g1     = (const float*)d_in[7];
    const float* W1g2     = (const float*)d_in[8];
    const float* b1g2     = (const float*)d_in[9];
    const float* W2g2     = (const float*)d_in[10];
    const float* b2g2     = (const float*)d_in[11];
    const float* gamma1g1 = (const float*)d_in[12];
    const float* beta1g1  = (const float*)d_in[13];
    const float* gamma2g1 = (const float*)d_in[14];
    const float* beta2g1  = (const float*)d_in[15];
    const float* gamma1g2 = (const float*)d_in[16];
    const float* beta1g2  = (const float*)d_in[17];
    const float* gamma2g2 = (const float*)d_in[18];
    const float* beta2g2  = (const float*)d_in[19];
    const float* Wout     = (const float*)d_in[20];
    const float* bout     = (const float*)d_in[21];
    const float* Wres     = (const float*)d_in[22];
    const float* bres     = (const float*)d_in[23];
    float* outp = (float*)d_out;

    char* p = (char*)d_ws;
    __bf16* geneb = (__bf16*)p;           p += (size_t)BATCH * NGRP * 2;
    __bf16* h1pre = (__bf16*)p;           p += (size_t)BATCH * NH1 * 2;
    __bf16* bufA  = (__bf16*)p;           p += (size_t)BATCH * NH1 * 2;
    __bf16* h1b   = (__bf16*)p;           p += (size_t)BATCH * NH2 * 2;
    __bf16* h2b   = (__bf16*)p;           p += (size_t)BATCH * NH2 * 2;
    __bf16* w1t   = (__bf16*)p;           p += (size_t)NH1 * 256 * 2;
    __bf16* w2at  = (__bf16*)p;           p += (size_t)NH2 * NH1 * 2;
    __bf16* w2bt  = (__bf16*)p;           p += (size_t)NH2 * NH1 * 2;
    float*  st    = (float*)p;
    float* s1a = st;          float* q1a = st + 512;
    float* s1b = st + 1024;   float* q1b = st + 1536;
    float* s2a = st + 2048;   float* q2a = st + 2560;
    float* s2b = st + 3072;   float* q2b = st + 3584;

    hipMemsetAsync(st, 0, 4096 * sizeof(float), stream);

    transpose_all<<<dim3(16, 16, 3), 256, 0, stream>>>(W1g1, W2g1, W2g2, w1t, w2at, w2bt);

    gene_kernel<<<BATCH, 256, 0, stream>>>(x, wgene, bgene, geneb);

    // layer1: branch1 MFMA GEMM (x<8) + branch2 K=3 (x==8)
    gemm1_fused<<<dim3(9, BATCH / 64), 256, 0, stream>>>(
        geneb, w1t, b1g1, h1pre, s1a, q1a,
        W1g2, b1g2, bufA, s2a, q2a);

    // layer2 both branches: bnrelu(A) @ WT^T + bias -> h1b/h2b, stats
    gemm2_dual<<<dim3(NH2 / 64, BATCH / 64, 2), 256, 0, stream>>>(
        h1pre, bufA, w2at, w2bt, b2g1, b2g2, h1b, h2b,
        s1b, q1b, s2b, q2b,
        s1a, q1a, gamma1g1, beta1g1,
        s2a, q2a, gamma1g2, beta1g2);

    final_kernel<<<BATCH / 4, 256, 0, stream>>>(
        h1b, h2b, geneb,
        s1b, q1b, gamma2g1, beta2g1,
        s2b, q2b, gamma2g2, beta2g2,
        Wout, bout, Wres, bres, outp);
}

// Round 5
// 273.467 us; speedup vs baseline: 1.7982x; 1.0144x over previous
//
#include <hip/hip_runtime.h>
#include <cstddef>

#define BATCH  8192
#define NFEAT  4096
#define NGRP   256
#define NSPLIT 253
#define NH1    512
#define NH2    256
#define EPSV   1e-5f

typedef __bf16 bf16_8 __attribute__((ext_vector_type(8)));
typedef float  f32x4  __attribute__((ext_vector_type(4)));

__constant__ int c_prefix[8] = {0,3,8,16,28,44,65,92};
__constant__ int c_gsize[8]  = {3,5,8,12,16,21,27,36};

// ---------------------------------------------------------------------------
// Kernel 1 (fused aux): blocks < 8192 compute one gene row; blocks
// [8192, 8576) do the three weight transposes (bf16, zero-padded K); the last
// block zeroes the stats buffer (replaces hipMemsetAsync).
// gene: LDS padded +8 floats per 128-feature block (stride 136); 8 lanes per
// group + shfl reduce; packed uint4 geneb stores.
// ---------------------------------------------------------------------------
__global__ __launch_bounds__(256) void gene_aux_kernel(
        const float* __restrict__ x, const float* __restrict__ wg,
        const float* __restrict__ bg, __bf16* __restrict__ geneb,
        const float* __restrict__ W1g1, const float* __restrict__ W2g1,
        const float* __restrict__ W2g2,
        __bf16* __restrict__ w1t, __bf16* __restrict__ w2at, __bf16* __restrict__ w2bt,
        float* __restrict__ st)
{
    __shared__ __align__(16) char smem[(NFEAT + 32 * 8) * 4 + NGRP * 4];
    int t = threadIdx.x;
    int bid = blockIdx.x;

    if (bid >= 8192) {
        int j = bid - 8192;
        if (j == 384) {           // stats zero: 4096 floats
            float4 z = {0.f, 0.f, 0.f, 0.f};
#pragma unroll
            for (int i = 0; i < 4; i++) *(float4*)&st[(t + 256 * i) * 4] = z;
            return;
        }
        // transpose job
        float (*tile)[33] = (float(*)[33])smem;
        int z = j >> 7, tid = j & 127;
        const float* src; __bf16* dst; int K, N, Kp;
        if (z == 0)      { src = W1g1; dst = w1t;  K = NSPLIT; N = NH1; Kp = 256; }
        else if (z == 1) { src = W2g1; dst = w2at; K = NH1;    N = NH2; Kp = NH1; }
        else             { src = W2g2; dst = w2bt; K = NH1;    N = NH2; Kp = NH1; }
        int ktiles = (K + 31) >> 5;
        if (tid >= ktiles * (N >> 5)) return;
        int kt = (tid % ktiles) * 32, nt = (tid / ktiles) * 32;
        int tx = t & 31, ty = t >> 5;
        for (int r = ty; r < 32; r += 8) {
            int k = kt + r, n = nt + tx;
            tile[r][tx] = (k < K && n < N) ? src[(size_t)k * N + n] : 0.f;
        }
        __syncthreads();
        for (int r = ty; r < 32; r += 8) {
            int n = nt + r, k = kt + tx;
            if (n < N && k < Kp) dst[(size_t)n * Kp + k] = (__bf16)tile[tx][r];
        }
        return;
    }

    // ---------------- gene row ----------------
    float* prod = (float*)smem;                    // NFEAT + 256 floats
    float* gout = prod + NFEAT + 32 * 8;           // NGRP floats
    size_t row = bid;
    const float4* xv = (const float4*)(x + row * NFEAT);
    const float4* wv = (const float4*)wg;
#pragma unroll
    for (int i = 0; i < 4; i++) {
        int idx = t + 256 * i;
        float4 a = xv[idx], w = wv[idx];
        float4 p; p.x = a.x*w.x; p.y = a.y*w.y; p.z = a.z*w.z; p.w = a.w*w.w;
        int f = idx * 4;
        *(float4*)&prod[f + ((f >> 7) << 3)] = p;
    }
    __syncthreads();
    int sub = t & 7, gidx = t >> 3;
    int gi  = gidx & 7, fbo = gidx >> 3;
    int pre = c_prefix[gi], len = c_gsize[gi];
#pragma unroll
    for (int s = 0; s < 8; s++) {
        int base = (4 * s + fbo) * 136 + pre;
        float v = 0.f;
        for (int j = sub; j < len; j += 8) v += prod[base + j];
        v += __shfl_down(v, 4, 8);
        v += __shfl_down(v, 2, 8);
        v += __shfl_down(v, 1, 8);
        if (sub == 0) gout[(s << 5) + gidx] = v;
    }
    __syncthreads();
    if (t < 32) {   // pack 8 bf16 per lane -> one uint4 store
        unsigned short up[8];
#pragma unroll
        for (int e = 0; e < 8; e++) {
            int g = t * 8 + e;
            __bf16 b = (__bf16)fmaxf(gout[g] + bg[g], 0.f);
            up[e] = *(unsigned short*)&b;
        }
        *(uint4*)((unsigned short*)geneb + row * NGRP + t * 8) = *(uint4*)up;
    }
}

// ---------------------------------------------------------------------------
// GEMM1 + fused b2l1: grid (9, 128). x<8: 64x64 MFMA tile of
// h1pre = geneb @ w1t^T + b1g1 (stats s1a/q1a). x==8: b2l1 for 64 rows:
// bufA = geneb[:,253:256] @ W1g2 + b1g2 (stats s2a/q2a).
// ---------------------------------------------------------------------------
__global__ __launch_bounds__(256) void gemm1_fused(
    const __bf16* __restrict__ geneb, const __bf16* __restrict__ w1t,
    const float* __restrict__ b1g1, __bf16* __restrict__ h1pre,
    float* __restrict__ s1a, float* __restrict__ q1a,
    const float* __restrict__ W1g2, const float* __restrict__ b1g2,
    __bf16* __restrict__ bufA, float* __restrict__ s2a, float* __restrict__ q2a)
{
    __shared__ __align__(16) char smem[19456];
    int t = threadIdx.x;

    if (blockIdx.x == 8) {
        float* Ws  = (float*)smem;
        float* bsh = Ws + 1536;
        float* gv  = bsh + 512;
        for (int i = t; i < 1536; i += 256) Ws[i] = W1g2[i];
        for (int i = t; i < 512; i += 256) bsh[i] = b1g2[i];
        int row0 = blockIdx.y * 64;
        if (t < 192)
            gv[t] = (float)geneb[(size_t)(row0 + t / 3) * NGRP + NSPLIT + (t % 3)];
        __syncthreads();
        int c0 = t, c1 = t + 256;
        float s0 = 0, q0 = 0, s1 = 0, q1 = 0;
        for (int r = 0; r < 64; r++) {
            float a = gv[3 * r], b = gv[3 * r + 1], c = gv[3 * r + 2];
            float v0 = bsh[c0] + a * Ws[c0] + b * Ws[512 + c0] + c * Ws[1024 + c0];
            float v1 = bsh[c1] + a * Ws[c1] + b * Ws[512 + c1] + c * Ws[1024 + c1];
            size_t base = (size_t)(row0 + r) * NH1;
            bufA[base + c0] = (__bf16)v0; bufA[base + c1] = (__bf16)v1;
            s0 += v0; q0 += v0 * v0; s1 += v1; q1 += v1 * v1;
        }
        atomicAdd(&s2a[c0], s0); atomicAdd(&q2a[c0], q0);
        atomicAdd(&s2a[c1], s1); atomicAdd(&q2a[c1], q1);
        return;
    }

    const int K = 256;
    __bf16 (*As)[72] = (__bf16(*)[72])smem;
    __bf16 (*Bs)[72] = (__bf16(*)[72])(smem + 9216);
    float* sred = (float*)(smem + 18432);
    float* qred = sred + 64;

    int n0 = blockIdx.x * 64;
    int m0 = blockIdx.y * 64;
    if (t < 64) { sred[t] = 0.f; qred[t] = 0.f; }

    int lane = t & 63, w = t >> 6;
    int wm = (w & 1) * 32, wn = (w >> 1) * 32;
    int fm = lane & 15, quad = lane >> 4;

    f32x4 acc[2][2];
#pragma unroll
    for (int i = 0; i < 2; i++)
#pragma unroll
        for (int j = 0; j < 2; j++) acc[i][j] = (f32x4){0.f, 0.f, 0.f, 0.f};

    int r0 = t >> 3;
    int kc = (t & 7) * 8;

    for (int kt = 0; kt < (K >> 6); kt++) {
        int kk = kt << 6;
        __syncthreads();
#pragma unroll
        for (int h = 0; h < 2; h++) {
            int row = r0 + h * 32;
            *(uint4*)&As[row][kc] = *(const uint4*)(geneb + (size_t)(m0 + row) * NGRP + kk + kc);
            *(uint4*)&Bs[row][kc] = *(const uint4*)(w1t + (size_t)(n0 + row) * K + kk + kc);
        }
        __syncthreads();
#pragma unroll
        for (int kc2 = 0; kc2 < 64; kc2 += 32) {
            bf16_8 a0 = *(const bf16_8*)&As[wm + fm][kc2 + quad * 8];
            bf16_8 a1 = *(const bf16_8*)&As[wm + 16 + fm][kc2 + quad * 8];
            bf16_8 b0 = *(const bf16_8*)&Bs[wn + fm][kc2 + quad * 8];
            bf16_8 b1 = *(const bf16_8*)&Bs[wn + 16 + fm][kc2 + quad * 8];
            acc[0][0] = __builtin_amdgcn_mfma_f32_16x16x32_bf16(a0, b0, acc[0][0], 0, 0, 0);
            acc[0][1] = __builtin_amdgcn_mfma_f32_16x16x32_bf16(a0, b1, acc[0][1], 0, 0, 0);
            acc[1][0] = __builtin_amdgcn_mfma_f32_16x16x32_bf16(a1, b0, acc[1][0], 0, 0, 0);
            acc[1][1] = __builtin_amdgcn_mfma_f32_16x16x32_bf16(a1, b1, acc[1][1], 0, 0, 0);
        }
    }

    float myS[2] = {0.f, 0.f}, myQ[2] = {0.f, 0.f};
#pragma unroll
    for (int j = 0; j < 2; j++) {
        int col = n0 + wn + j * 16 + fm;
        float bv = b1g1[col];
#pragma unroll
        for (int i = 0; i < 2; i++)
#pragma unroll
            for (int r = 0; r < 4; r++) {
                float v = acc[i][j][r] + bv;
                int row = m0 + wm + i * 16 + quad * 4 + r;
                h1pre[(size_t)row * NH1 + col] = (__bf16)v;
                myS[j] += v; myQ[j] += v * v;
            }
    }
#pragma unroll
    for (int j = 0; j < 2; j++) {
        atomicAdd(&sred[wn + j * 16 + fm], myS[j]);
        atomicAdd(&qred[wn + j * 16 + fm], myQ[j]);
    }
    __syncthreads();
    if (t < 64) {
        atomicAdd(&s1a[n0 + t], sred[t]);
        atomicAdd(&q1a[n0 + t], qred[t]);
    }
}

// ---------------------------------------------------------------------------
// GEMM2 dual (both branches, blockIdx.z selects): K=512, N=256, BN+ReLU fused
// on A-load from batch stats.
// ---------------------------------------------------------------------------
__global__ __launch_bounds__(256) void gemm2_dual(
    const __bf16* A0, const __bf16* A1,
    const __bf16* WT0, const __bf16* WT1,
    const float* bias0, const float* bias1,
    __bf16* C0, __bf16* C1,
    float* csum0, float* csq0, float* csum1, float* csq1,
    const float* as0, const float* aq0, const float* ag0, const float* ab0,
    const float* as1, const float* aq1, const float* ag1, const float* ab1)
{
    const int K = NH1, n_total = NH2;
    __shared__ __align__(16) __bf16 As[64][72];
    __shared__ __align__(16) __bf16 Bs[64][72];
    __shared__ float bnsc[NH1];
    __shared__ float bnsh[NH1];
    __shared__ float sred[64];
    __shared__ float qred[64];

    int z = blockIdx.z;
    const __bf16* A    = z ? A1 : A0;
    const __bf16* WT   = z ? WT1 : WT0;
    const float*  bias = z ? bias1 : bias0;
    __bf16*       C    = z ? C1 : C0;
    float* csum = z ? csum1 : csum0;
    float* csq  = z ? csq1  : csq0;
    const float* a_sum = z ? as1 : as0;
    const float* a_sq  = z ? aq1 : aq0;
    const float* a_g   = z ? ag1 : ag0;
    const float* a_b   = z ? ab1 : ab0;

    int t = threadIdx.x;
    int n0 = blockIdx.x * 64;
    int m0 = blockIdx.y * 64;
    {
        const float invB = 1.f / (float)BATCH;
        for (int k = t; k < K; k += 256) {
            float mu  = a_sum[k] * invB;
            float var = a_sq[k] * invB - mu * mu;
            float sc  = a_g[k] * rsqrtf(var + EPSV);
            bnsc[k] = sc;
            bnsh[k] = a_b[k] - mu * sc;
        }
    }
    if (t < 64) { sred[t] = 0.f; qred[t] = 0.f; }

    int lane = t & 63, w = t >> 6;
    int wm = (w & 1) * 32, wn = (w >> 1) * 32;
    int fm = lane & 15, quad = lane >> 4;

    f32x4 acc[2][2];
#pragma unroll
    for (int i = 0; i < 2; i++)
#pragma unroll
        for (int j = 0; j < 2; j++) acc[i][j] = (f32x4){0.f, 0.f, 0.f, 0.f};

    int r0 = t >> 3;
    int kc = (t & 7) * 8;

    for (int kt = 0; kt < (K >> 6); kt++) {
        int kk = kt << 6;
        __syncthreads();
#pragma unroll
        for (int h = 0; h < 2; h++) {
            int row = r0 + h * 32;
            uint4 raw = *(const uint4*)(A + (size_t)(m0 + row) * K + kk + kc);
            __bf16 vals[8];
#pragma unroll
            for (int c = 0; c < 4; c++) {
                unsigned uu = (&raw.x)[c];
                int kg = kk + kc + 2 * c;
                float flo = __uint_as_float(uu << 16);
                float fhi = __uint_as_float(uu & 0xffff0000u);
                flo = fmaxf(fmaf(flo, bnsc[kg],     bnsh[kg]),     0.f);
                fhi = fmaxf(fmaf(fhi, bnsc[kg + 1], bnsh[kg + 1]), 0.f);
                vals[2 * c]     = (__bf16)flo;
                vals[2 * c + 1] = (__bf16)fhi;
            }
            *(bf16_8*)&As[row][kc] = *(bf16_8*)vals;
            *(uint4*)&Bs[row][kc] = *(const uint4*)(WT + (size_t)(n0 + row) * K + kk + kc);
        }
        __syncthreads();
#pragma unroll
        for (int kc2 = 0; kc2 < 64; kc2 += 32) {
            bf16_8 a0 = *(const bf16_8*)&As[wm + fm][kc2 + quad * 8];
            bf16_8 a1 = *(const bf16_8*)&As[wm + 16 + fm][kc2 + quad * 8];
            bf16_8 b0 = *(const bf16_8*)&Bs[wn + fm][kc2 + quad * 8];
            bf16_8 b1 = *(const bf16_8*)&Bs[wn + 16 + fm][kc2 + quad * 8];
            acc[0][0] = __builtin_amdgcn_mfma_f32_16x16x32_bf16(a0, b0, acc[0][0], 0, 0, 0);
            acc[0][1] = __builtin_amdgcn_mfma_f32_16x16x32_bf16(a0, b1, acc[0][1], 0, 0, 0);
            acc[1][0] = __builtin_amdgcn_mfma_f32_16x16x32_bf16(a1, b0, acc[1][0], 0, 0, 0);
            acc[1][1] = __builtin_amdgcn_mfma_f32_16x16x32_bf16(a1, b1, acc[1][1], 0, 0, 0);
        }
    }

    float myS[2] = {0.f, 0.f}, myQ[2] = {0.f, 0.f};
#pragma unroll
    for (int j = 0; j < 2; j++) {
        int col = n0 + wn + j * 16 + fm;
        float bv = bias[col];
#pragma unroll
        for (int i = 0; i < 2; i++)
#pragma unroll
            for (int r = 0; r < 4; r++) {
                float v = acc[i][j][r] + bv;
                int row = m0 + wm + i * 16 + quad * 4 + r;
                C[(size_t)row * n_total + col] = (__bf16)v;
                myS[j] += v; myQ[j] += v * v;
            }
    }
#pragma unroll
    for (int j = 0; j < 2; j++) {
        atomicAdd(&sred[wn + j * 16 + fm], myS[j]);
        atomicAdd(&qred[wn + j * 16 + fm], myQ[j]);
    }
    __syncthreads();
    if (t < 64) {
        atomicAdd(&csum[n0 + t], sred[t]);
        atomicAdd(&csq[n0 + t], qred[t]);
    }
}

// ---------------------------------------------------------------------------
// Final: out[b] = bnrelu(h1b)@Wout[0:256] + bnrelu(h2b)@Wout[256:512]
//               + geneb[b,:]@Wres + b_out + b_res.
// One wave per 2 rows (params loaded once, reused), 4 cols/lane.
// ---------------------------------------------------------------------------
__global__ __launch_bounds__(256) void final_kernel(
    const __bf16* __restrict__ h1, const __bf16* __restrict__ h2,
    const __bf16* __restrict__ geneb,
    const float* __restrict__ s1, const float* __restrict__ q1,
    const float* __restrict__ gm1, const float* __restrict__ bt1,
    const float* __restrict__ s2, const float* __restrict__ q2,
    const float* __restrict__ gm2, const float* __restrict__ bt2,
    const float* __restrict__ Wout, const float* __restrict__ bo,
    const float* __restrict__ Wres, const float* __restrict__ br,
    float* __restrict__ outp)
{
    int t = threadIdx.x, lane = t & 63, wv = t >> 6;
    int row0 = blockIdx.x * 8 + wv * 2;
    int c = lane * 4;
    const float invB = 1.f / (float)BATCH;
    float4 vs1 = *(const float4*)&s1[c],  vq1 = *(const float4*)&q1[c];
    float4 vg1 = *(const float4*)&gm1[c], vb1 = *(const float4*)&bt1[c];
    float4 vs2 = *(const float4*)&s2[c],  vq2 = *(const float4*)&q2[c];
    float4 vg2 = *(const float4*)&gm2[c], vb2 = *(const float4*)&bt2[c];
    float4 wo1 = *(const float4*)&Wout[c];
    float4 wo2 = *(const float4*)&Wout[NH2 + c];
    float4 wr  = *(const float4*)&Wres[c];
    // precompute BN affine per column: v = h*sc + sh
    float4 sc1, sh1, sc2, sh2;
#pragma unroll
    for (int e = 0; e < 4; e++) {
        float mu  = (&vs1.x)[e] * invB;
        float var = (&vq1.x)[e] * invB - mu * mu;
        float sc  = (&vg1.x)[e] * rsqrtf(var + EPSV);
        (&sc1.x)[e] = sc; (&sh1.x)[e] = (&vb1.x)[e] - mu * sc;
        mu  = (&vs2.x)[e] * invB;
        var = (&vq2.x)[e] * invB - mu * mu;
        sc  = (&vg2.x)[e] * rsqrtf(var + EPSV);
        (&sc2.x)[e] = sc; (&sh2.x)[e] = (&vb2.x)[e] - mu * sc;
    }
#pragma unroll
    for (int rr = 0; rr < 2; rr++) {
        int row = row0 + rr;
        ushort4 u1 = *(const ushort4*)((const unsigned short*)h1 + (size_t)row * NH2 + c);
        ushort4 u2 = *(const ushort4*)((const unsigned short*)h2 + (size_t)row * NH2 + c);
        ushort4 ug = *(const ushort4*)((const unsigned short*)geneb + (size_t)row * NGRP + c);
        float acc = 0.f;
#pragma unroll
        for (int e = 0; e < 4; e++) {
            float h1f = __uint_as_float((unsigned)(&u1.x)[e] << 16);
            float h2f = __uint_as_float((unsigned)(&u2.x)[e] << 16);
            float gvf = __uint_as_float((unsigned)(&ug.x)[e] << 16);
            acc += fmaxf(fmaf(h1f, (&sc1.x)[e], (&sh1.x)[e]), 0.f) * (&wo1.x)[e];
            acc += fmaxf(fmaf(h2f, (&sc2.x)[e], (&sh2.x)[e]), 0.f) * (&wo2.x)[e];
            acc += gvf * (&wr.x)[e];
        }
#pragma unroll
        for (int off = 32; off > 0; off >>= 1) acc += __shfl_down(acc, off, 64);
        if (lane == 0) outp[row] = acc + bo[0] + br[0];
    }
}

extern "C" void kernel_launch(void* const* d_in, const int* in_sizes, int n_in,
                              void* d_out, int out_size, void* d_ws, size_t ws_size,
                              hipStream_t stream)
{
    (void)in_sizes; (void)n_in; (void)out_size; (void)ws_size;
    const float* x        = (const float*)d_in[0];
    const float* wgene    = (const float*)d_in[2];
    const float* bgene    = (const float*)d_in[3];
    const float* W1g1     = (const float*)d_in[4];
    const float* b1g1     = (const float*)d_in[5];
    const float* W2g1     = (const float*)d_in[6];
    const float* b2g1     = (const float*)d_in[7];
    const float* W1g2     = (const float*)d_in[8];
    const float* b1g2     = (const float*)d_in[9];
    const float* W2g2     = (const float*)d_in[10];
    const float* b2g2     = (const float*)d_in[11];
    const float* gamma1g1 = (const float*)d_in[12];
    const float* beta1g1  = (const float*)d_in[13];
    const float* gamma2g1 = (const float*)d_in[14];
    const float* beta2g1  = (const float*)d_in[15];
    const float* gamma1g2 = (const float*)d_in[16];
    const float* beta1g2  = (const float*)d_in[17];
    const float* gamma2g2 = (const float*)d_in[18];
    const float* beta2g2  = (const float*)d_in[19];
    const float* Wout     = (const float*)d_in[20];
    const float* bout     = (const float*)d_in[21];
    const float* Wres     = (const float*)d_in[22];
    const float* bres     = (const float*)d_in[23];
    float* outp = (float*)d_out;

    char* p = (char*)d_ws;
    __bf16* geneb = (__bf16*)p;           p += (size_t)BATCH * NGRP * 2;
    __bf16* h1pre = (__bf16*)p;           p += (size_t)BATCH * NH1 * 2;
    __bf16* bufA  = (__bf16*)p;           p += (size_t)BATCH * NH1 * 2;
    __bf16* h1b   = (__bf16*)p;           p += (size_t)BATCH * NH2 * 2;
    __bf16* h2b   = (__bf16*)p;           p += (size_t)BATCH * NH2 * 2;
    __bf16* w1t   = (__bf16*)p;           p += (size_t)NH1 * 256 * 2;
    __bf16* w2at  = (__bf16*)p;           p += (size_t)NH2 * NH1 * 2;
    __bf16* w2bt  = (__bf16*)p;           p += (size_t)NH2 * NH1 * 2;
    float*  st    = (float*)p;
    float* s1a = st;          float* q1a = st + 512;
    float* s1b = st + 1024;   float* q1b = st + 1536;
    float* s2a = st + 2048;   float* q2a = st + 2560;
    float* s2b = st + 3072;   float* q2b = st + 3584;

    // gene rows + weight transposes + stat zeroing, one launch
    gene_aux_kernel<<<8192 + 384 + 1, 256, 0, stream>>>(
        x, wgene, bgene, geneb, W1g1, W2g1, W2g2, w1t, w2at, w2bt, st);

    // layer1: branch1 MFMA GEMM (x<8) + branch2 K=3 (x==8)
    gemm1_fused<<<dim3(9, BATCH / 64), 256, 0, stream>>>(
        geneb, w1t, b1g1, h1pre, s1a, q1a,
        W1g2, b1g2, bufA, s2a, q2a);

    // layer2 both branches: bnrelu(A) @ WT^T + bias -> h1b/h2b, stats
    gemm2_dual<<<dim3(NH2 / 64, BATCH / 64, 2), 256, 0, stream>>>(
        h1pre, bufA, w2at, w2bt, b2g1, b2g2, h1b, h2b,
        s1b, q1b, s2b, q2b,
        s1a, q1a, gamma1g1, beta1g1,
        s2a, q2a, gamma1g2, beta1g2);

    final_kernel<<<BATCH / 8, 256, 0, stream>>>(
        h1b, h2b, geneb,
        s1b, q1b, gamma2g1, beta2g1,
        s2b, q2b, gamma2g2, beta2g2,
        Wout, bout, Wres, bres, outp);
}